// Round 1
// baseline (668.376 us; speedup 1.0000x reference)
//
#include <hip/hip_runtime.h>
#include <math.h>

// ---------------- workspace layout (float offsets) ----------------
// proj  [2][8][8][1024]            @ 0        (131072)
// conv  [2][4][8][8][1024]         @ 131072   (524288)
// mean  [2][4][8]                  @ 655360   (64)
// rstd  [2][4][8]                  @ 655424   (64)
// c     [1]                        @ 655488
// Qt    [64][1024]                 @ 655616   (65536)
// Kt    [64][1024]                 @ 721152   (65536)
namespace {
constexpr int PROJ_OFF = 0;
constexpr int CONV_OFF = 131072;
constexpr int MEAN_OFF = 655360;
constexpr int RSTD_OFF = 655424;
constexpr int C_OFF    = 655488;
constexpr int QT_OFF   = 655616;
constexpr int KT_OFF   = 721152;

// ---------------- kernel 1: projection q/k = X . W_pq ----------------
__global__ __launch_bounds__(256) void proj_kernel(
    const float* __restrict__ Q, const float* __restrict__ K,
    const float* __restrict__ Wpq, float* __restrict__ proj) {
  const int lane = threadIdx.x & 63;
  const int wave = (blockIdx.x * blockDim.x + threadIdx.x) >> 6;
  const int nw = (gridDim.x * blockDim.x) >> 6;
  const float w = Wpq[lane];
  for (int row = wave; row < 2 * 65536; row += nw) {
    const float* src = (row < 65536) ? Q : K;
    const int r = row & 65535;
    float v = src[(size_t)r * 64 + lane] * w;
#pragma unroll
    for (int m = 32; m >= 1; m >>= 1) v += __shfl_xor(v, m, 64);
    if (lane == 0) proj[row] = v;
  }
}

// ---------------- kernel 2: conv1d (4 filters x 2 paths) ----------------
__global__ __launch_bounds__(256) void conv_kernel(
    const float* __restrict__ proj,
    const float* __restrict__ wq0, const float* __restrict__ bq0,
    const float* __restrict__ wq1, const float* __restrict__ bq1,
    const float* __restrict__ wq2, const float* __restrict__ bq2,
    const float* __restrict__ wq3, const float* __restrict__ bq3,
    const float* __restrict__ wk0, const float* __restrict__ bk0,
    const float* __restrict__ wk1, const float* __restrict__ bk1,
    const float* __restrict__ wk2, const float* __restrict__ bk2,
    const float* __restrict__ wk3, const float* __restrict__ bk3,
    float* __restrict__ conv) {
  __shared__ float xs[8][1024];
  __shared__ float wsm[8 * 8 * 9];
  __shared__ float bsm[8];
  const int tid = threadIdx.x;
  const int blk = blockIdx.x;            // 64 blocks: (path, filt, batch)
  const int path = blk >> 5, fi = (blk >> 3) & 3, bb = blk & 7;
  const int F = (0x9731 >> (fi * 4)) & 0xF;   // 1,3,7,9
  const int pad = (F - 1) >> 1;
  const float* wp;
  const float* bp;
  if (path == 0) {
    wp = fi == 0 ? wq0 : fi == 1 ? wq1 : fi == 2 ? wq2 : wq3;
    bp = fi == 0 ? bq0 : fi == 1 ? bq1 : fi == 2 ? bq2 : bq3;
  } else {
    wp = fi == 0 ? wk0 : fi == 1 ? wk1 : fi == 2 ? wk2 : wk3;
    bp = fi == 0 ? bk0 : fi == 1 ? bk1 : fi == 2 ? bk2 : bk3;
  }
  for (int e = tid; e < 8192; e += 256)
    xs[e >> 10][e & 1023] = proj[path * 65536 + bb * 8192 + e];
  for (int e = tid; e < 64 * F; e += 256) wsm[e] = wp[e];
  if (tid < 8) bsm[tid] = bp[tid];
  __syncthreads();
  float* outp = conv + ((size_t)(path * 4 + fi) * 8 + bb) * 8192;
  for (int e = tid; e < 8192; e += 256) {
    const int o = e >> 10, l = e & 1023;
    float acc = bsm[o];
    for (int c = 0; c < 8; ++c) {
      const float* wrow = &wsm[(o * 8 + c) * F];
      for (int f = 0; f < F; ++f) {
        const int pos = l + f - pad;
        if (pos >= 0 && pos < 1024) acc = fmaf(xs[c][pos], wrow[f], acc);
      }
    }
    outp[e] = acc;
  }
}

// ---------------- kernel 3: BN batch stats + scalar c ----------------
__global__ __launch_bounds__(256) void stats_kernel(
    const float* __restrict__ conv,
    const float* __restrict__ Wbq, const float* __restrict__ Wbk,
    float* __restrict__ meanw, float* __restrict__ rstdw,
    float* __restrict__ cw) {
  __shared__ float r1[256], r2[256];
  const int tid = threadIdx.x, blk = blockIdx.x;  // blk = path*32+fi*8+o
  const int o = blk & 7;
  const size_t base = (size_t)(blk >> 3) * 8 * 8192 + (size_t)o * 1024;
  float s = 0.f, ss = 0.f;
  for (int e = tid; e < 8192; e += 256) {
    const int bb = e >> 10, l = e & 1023;
    const float v = conv[base + (size_t)bb * 8192 + l];
    s += v;
    ss += v * v;
  }
  r1[tid] = s;
  r2[tid] = ss;
  __syncthreads();
  for (int st = 128; st > 0; st >>= 1) {
    if (tid < st) {
      r1[tid] += r1[tid + st];
      r2[tid] += r2[tid + st];
    }
    __syncthreads();
  }
  if (tid == 0) {
    const float mean = r1[0] * (1.f / 8192.f);
    const float var = r2[0] * (1.f / 8192.f) - mean * mean;
    meanw[blk] = mean;
    rstdw[blk] = rsqrtf(fmaxf(var, 0.f) + 1e-5f);
  }
  if (blk == 0 && tid == 0) {
    float d = 0.f;
    for (int i = 0; i < 64; ++i) d += Wbq[i] * Wbk[i];
    cw[0] = d * 0.125f;  // / sqrt(64)
  }
}

__device__ inline float bn_elu(float v, float mean, float rstd, float g,
                               float be) {
  const float x = (v - mean) * rstd * g + be;
  return x > 0.f ? x : expm1f(x);
}

// ---------------- kernel 4: Q gather + BN/ELU + top-1024-of-4096 ----------------
__global__ __launch_bounds__(256) void qsort_kernel(
    const float* __restrict__ conv, const float* __restrict__ meanw,
    const float* __restrict__ rstdw, const float* __restrict__ bng,
    const float* __restrict__ bnb, float* __restrict__ Qt) {
  __shared__ float a[4096];
  const int tid = threadIdx.x, blk = blockIdx.x;  // blk = b'*8 + h'
  const int bp = blk >> 3, hp = blk & 7;
  const int fi = bp >> 1;
  const int bb = (bp & 1) * 4 + (hp >> 1);
  for (int j = 0; j < 4; ++j) {
    const int hh = (hp & 1) * 4 + j;
    const float mean = meanw[fi * 8 + hh], rstd = rstdw[fi * 8 + hh];
    const float g = bng[hh], be = bnb[hh];
    const float* src = conv + ((size_t)fi * 8 + bb) * 8192 + hh * 1024;
    for (int l = tid; l < 1024; l += 256)
      a[j * 1024 + l] = bn_elu(src[l], mean, rstd, g, be);
  }
  __syncthreads();
  for (int k = 2; k <= 4096; k <<= 1)
    for (int j = k >> 1; j > 0; j >>= 1) {
      for (int idx = tid; idx < 4096; idx += 256) {
        const int ixj = idx ^ j;
        if (ixj > idx) {
          const float x = a[idx], y = a[ixj];
          const bool up = (idx & k) == 0;
          if (up ? (x < y) : (x > y)) {  // descending sort
            a[idx] = y;
            a[ixj] = x;
          }
        }
      }
      __syncthreads();
    }
  for (int l = tid; l < 1024; l += 256) Qt[blk * 1024 + l] = a[l];
}

// ---------------- kernel 5: K gather + BN/ELU + mean4 + sort ----------------
__global__ __launch_bounds__(256) void ksort_kernel(
    const float* __restrict__ conv, const float* __restrict__ meanw,
    const float* __restrict__ rstdw, const float* __restrict__ bng,
    const float* __restrict__ bnb, float* __restrict__ Kt) {
  __shared__ float a[1024];
  const int tid = threadIdx.x, blk = blockIdx.x;
  const int bp = blk >> 3, hp = blk & 7;
  const int fi = bp >> 1;
  const int bb = (bp & 1) * 4 + (hp >> 1);
  for (int l = tid; l < 1024; l += 256) {
    float sum = 0.f;
    for (int j = 0; j < 4; ++j) {
      const int hh = (hp & 1) * 4 + j;
      const float mean = meanw[32 + fi * 8 + hh];
      const float rstd = rstdw[32 + fi * 8 + hh];
      const float v = conv[((size_t)(4 + fi) * 8 + bb) * 8192 + hh * 1024 + l];
      sum += bn_elu(v, mean, rstd, bng[hh], bnb[hh]);
    }
    a[l] = sum * 0.25f;
  }
  __syncthreads();
  for (int k = 2; k <= 1024; k <<= 1)
    for (int j = k >> 1; j > 0; j >>= 1) {
      for (int idx = tid; idx < 1024; idx += 256) {
        const int ixj = idx ^ j;
        if (ixj > idx) {
          const float x = a[idx], y = a[ixj];
          const bool up = (idx & k) == 0;
          if (up ? (x < y) : (x > y)) {
            a[idx] = y;
            a[ixj] = x;
          }
        }
      }
      __syncthreads();
    }
  for (int l = tid; l < 1024; l += 256) Kt[blk * 1024 + l] = a[l];
}

// ---------------- kernel 6: fused softmax(attn) write + PV ----------------
__global__ __launch_bounds__(256) void attn_kernel(
    const float* __restrict__ V, const float* __restrict__ Qt,
    const float* __restrict__ Kt, const float* __restrict__ cw,
    float* __restrict__ ctx, float* __restrict__ attn) {
  __shared__ float Kts[1024];
  __shared__ float E[32][256];
  __shared__ float sq[32], mq[32], rz[32];
  const int tid = threadIdx.x;
  // XCD-aware swizzle (2048 % 8 == 0 -> bijective)
  const int cpx = gridDim.x >> 3;
  const int wg = (blockIdx.x & 7) * cpx + (blockIdx.x >> 3);
  const int bh = wg >> 5, qt = wg & 31;
  const int qbase = qt * 32;
  const float cval = cw[0];
  for (int t = tid; t < 1024; t += 256) Kts[t] = Kt[bh * 1024 + t];
  __syncthreads();
  if (tid < 32) {
    const float s = cval * Qt[bh * 1024 + qbase + tid];
    sq[tid] = s;
    mq[tid] = fmaxf(s * Kts[0], s * Kts[1023]);  // Kt sorted desc
  }
  __syncthreads();
  {  // pass 1: row sums Z (8 lanes per q-row)
    const int q = tid >> 3, kl = tid & 7;
    const float s = sq[q], m = mq[q];
    float z = 0.f;
    for (int k = kl; k < 1024; k += 8) z += __expf(s * Kts[k] - m);
    z += __shfl_xor(z, 1, 64);
    z += __shfl_xor(z, 2, 64);
    z += __shfl_xor(z, 4, 64);
    if (kl == 0) rz[q] = 1.f / z;
  }
  __syncthreads();
  float acc[8] = {0.f, 0.f, 0.f, 0.f, 0.f, 0.f, 0.f, 0.f};
  const int wv = tid >> 6, lane = tid & 63;
  const float* Vb = V + (size_t)bh * 65536;
  float* arow = attn + (size_t)bh * 1048576 + (size_t)qbase * 1024;
  for (int ch = 0; ch < 4; ++ch) {
    const int k0 = ch * 256;
    const float kv = Kts[k0 + tid];
#pragma unroll 4
    for (int qq = 0; qq < 32; ++qq) {
      const float val = __expf(sq[qq] * kv - mq[qq]) * rz[qq];
      E[qq][tid] = val;
      arow[(size_t)qq * 1024 + k0 + tid] = val;  // coalesced 1KB/iter
    }
    __syncthreads();
    for (int k = 0; k < 256; k += 4) {
      const float v0 = Vb[(size_t)(k0 + k) * 64 + lane];
      const float v1 = Vb[(size_t)(k0 + k + 1) * 64 + lane];
      const float v2 = Vb[(size_t)(k0 + k + 2) * 64 + lane];
      const float v3 = Vb[(size_t)(k0 + k + 3) * 64 + lane];
#pragma unroll
      for (int j = 0; j < 8; ++j) {
        const float4 e4 = *(const float4*)&E[wv * 8 + j][k];  // broadcast
        acc[j] = fmaf(e4.x, v0, acc[j]);
        acc[j] = fmaf(e4.y, v1, acc[j]);
        acc[j] = fmaf(e4.z, v2, acc[j]);
        acc[j] = fmaf(e4.w, v3, acc[j]);
      }
    }
    __syncthreads();
  }
#pragma unroll
  for (int j = 0; j < 8; ++j)
    ctx[((size_t)bh * 1024 + qbase + wv * 8 + j) * 64 + lane] = acc[j];
}

}  // namespace

extern "C" void kernel_launch(void* const* d_in, const int* in_sizes, int n_in,
                              void* d_out, int out_size, void* d_ws,
                              size_t ws_size, hipStream_t stream) {
  const float* Q = (const float*)d_in[0];
  const float* K = (const float*)d_in[1];
  const float* V = (const float*)d_in[2];
  const float* Wpq = (const float*)d_in[3];
  const float* Wbq = (const float*)d_in[4];
  const float* Wbk = (const float*)d_in[5];
  const float* bng = (const float*)d_in[6];
  const float* bnb = (const float*)d_in[7];
  // d_in[8] = attn_mask (all ones, unused)
  // dict order: cq_w{i}, cq_b{i}, ck_w{i}, ck_b{i} per filter i
  const float* cqw[4] = {(const float*)d_in[9], (const float*)d_in[13],
                         (const float*)d_in[17], (const float*)d_in[21]};
  const float* cqb[4] = {(const float*)d_in[10], (const float*)d_in[14],
                         (const float*)d_in[18], (const float*)d_in[22]};
  const float* ckw[4] = {(const float*)d_in[11], (const float*)d_in[15],
                         (const float*)d_in[19], (const float*)d_in[23]};
  const float* ckb[4] = {(const float*)d_in[12], (const float*)d_in[16],
                         (const float*)d_in[20], (const float*)d_in[24]};

  float* ws = (float*)d_ws;
  float* proj = ws + PROJ_OFF;
  float* conv = ws + CONV_OFF;
  float* meanw = ws + MEAN_OFF;
  float* rstdw = ws + RSTD_OFF;
  float* cw = ws + C_OFF;
  float* Qtp = ws + QT_OFF;
  float* Ktp = ws + KT_OFF;
  float* ctx = (float*)d_out;
  float* attn = ctx + (size_t)8 * 8 * 1024 * 64;

  proj_kernel<<<512, 256, 0, stream>>>(Q, K, Wpq, proj);
  conv_kernel<<<64, 256, 0, stream>>>(
      proj, cqw[0], cqb[0], cqw[1], cqb[1], cqw[2], cqb[2], cqw[3], cqb[3],
      ckw[0], ckb[0], ckw[1], ckb[1], ckw[2], ckb[2], ckw[3], ckb[3], conv);
  stats_kernel<<<64, 256, 0, stream>>>(conv, Wbq, Wbk, meanw, rstdw, cw);
  qsort_kernel<<<64, 256, 0, stream>>>(conv, meanw, rstdw, bng, bnb, Qtp);
  ksort_kernel<<<64, 256, 0, stream>>>(conv, meanw, rstdw, bng, bnb, Ktp);
  attn_kernel<<<2048, 256, 0, stream>>>(V, Qtp, Ktp, cw, ctx, attn);
}

// Round 2
// 470.690 us; speedup vs baseline: 1.4200x; 1.4200x over previous
//
#include <hip/hip_runtime.h>
#include <math.h>

// ---------------- workspace layout (float offsets) ----------------
// proj  [2][8][8][1024]            @ 0        (131072)
// conv  [2][4][8][8][1024]         @ 131072   (524288)
// mean  [2][4][8]                  @ 655360   (64)
// rstd  [2][4][8]                  @ 655424   (64)
// c     [1]                        @ 655488
// Qt    [64][1024]                 @ 655616   (65536)
// Kt    [64][1024]                 @ 721152   (65536)
namespace {
constexpr int PROJ_OFF = 0;
constexpr int CONV_OFF = 131072;
constexpr int MEAN_OFF = 655360;
constexpr int RSTD_OFF = 655424;
constexpr int C_OFF    = 655488;
constexpr int QT_OFF   = 655616;
constexpr int KT_OFF   = 721152;

// ---------------- kernel 1: projection q/k = X . W_pq (1 row/thread) -------
__global__ __launch_bounds__(256) void proj_kernel(
    const float* __restrict__ Q, const float* __restrict__ K,
    const float* __restrict__ Wpq, float* __restrict__ proj) {
  __shared__ float wsh[64];
  const int tid = threadIdx.x;
  if (tid < 64) wsh[tid] = Wpq[tid];
  __syncthreads();
  const int row = blockIdx.x * 256 + tid;  // 0..131071
  const float* src = (row < 65536) ? (Q + (size_t)row * 64)
                                   : (K + (size_t)(row - 65536) * 64);
  float acc = 0.f;
#pragma unroll
  for (int j = 0; j < 16; ++j) {
    const float4 v = *(const float4*)(src + j * 4);
    acc = fmaf(v.x, wsh[j * 4 + 0], acc);
    acc = fmaf(v.y, wsh[j * 4 + 1], acc);
    acc = fmaf(v.z, wsh[j * 4 + 2], acc);
    acc = fmaf(v.w, wsh[j * 4 + 3], acc);
  }
  proj[row] = acc;
}

// ---------------- kernel 2: conv1d (4 filters x 2 paths) ----------------
template <int F>
__device__ void conv_body(const float* __restrict__ xs,
                          const float* __restrict__ wsm,
                          const float* __restrict__ bsm,
                          float* __restrict__ outp, int tid) {
  constexpr int pad = (F - 1) / 2;
  for (int e = tid; e < 8192; e += 256) {
    const int o = e >> 10, l = e & 1023;
    float acc = bsm[o];
#pragma unroll
    for (int c = 0; c < 8; ++c) {
      const float* wrow = &wsm[(o * 8 + c) * F];
#pragma unroll
      for (int f = 0; f < F; ++f) {
        const int pos = l + f - pad;
        if (pos >= 0 && pos < 1024) acc = fmaf(xs[c * 1024 + pos], wrow[f], acc);
      }
    }
    outp[e] = acc;
  }
}

__global__ __launch_bounds__(256) void conv_kernel(
    const float* __restrict__ proj,
    const float* __restrict__ wq0, const float* __restrict__ bq0,
    const float* __restrict__ wq1, const float* __restrict__ bq1,
    const float* __restrict__ wq2, const float* __restrict__ bq2,
    const float* __restrict__ wq3, const float* __restrict__ bq3,
    const float* __restrict__ wk0, const float* __restrict__ bk0,
    const float* __restrict__ wk1, const float* __restrict__ bk1,
    const float* __restrict__ wk2, const float* __restrict__ bk2,
    const float* __restrict__ wk3, const float* __restrict__ bk3,
    float* __restrict__ conv) {
  __shared__ float xs[8 * 1024];
  __shared__ float wsm[8 * 8 * 9];
  __shared__ float bsm[8];
  const int tid = threadIdx.x;
  const int blk = blockIdx.x;  // 64 blocks: (path, filt, batch)
  const int path = blk >> 5, fi = (blk >> 3) & 3, bb = blk & 7;
  const int F = (0x9731 >> (fi * 4)) & 0xF;  // 1,3,7,9
  const float* wp;
  const float* bp;
  if (path == 0) {
    wp = fi == 0 ? wq0 : fi == 1 ? wq1 : fi == 2 ? wq2 : wq3;
    bp = fi == 0 ? bq0 : fi == 1 ? bq1 : fi == 2 ? bq2 : bq3;
  } else {
    wp = fi == 0 ? wk0 : fi == 1 ? wk1 : fi == 2 ? wk2 : wk3;
    bp = fi == 0 ? bk0 : fi == 1 ? bk1 : fi == 2 ? bk2 : bk3;
  }
  for (int e = tid; e < 8192; e += 256)
    xs[e] = proj[path * 65536 + bb * 8192 + e];
  for (int e = tid; e < 64 * F; e += 256) wsm[e] = wp[e];
  if (tid < 8) bsm[tid] = bp[tid];
  __syncthreads();
  float* outp = conv + ((size_t)(path * 4 + fi) * 8 + bb) * 8192;
  if (fi == 0)
    conv_body<1>(xs, wsm, bsm, outp, tid);
  else if (fi == 1)
    conv_body<3>(xs, wsm, bsm, outp, tid);
  else if (fi == 2)
    conv_body<7>(xs, wsm, bsm, outp, tid);
  else
    conv_body<9>(xs, wsm, bsm, outp, tid);
}

// ---------------- kernel 3: BN batch stats + scalar c ----------------
__global__ __launch_bounds__(256) void stats_kernel(
    const float* __restrict__ conv,
    const float* __restrict__ Wbq, const float* __restrict__ Wbk,
    float* __restrict__ meanw, float* __restrict__ rstdw,
    float* __restrict__ cw) {
  __shared__ float r1[256], r2[256];
  const int tid = threadIdx.x, blk = blockIdx.x;  // blk = path*32+fi*8+o
  const int o = blk & 7;
  const size_t base = (size_t)(blk >> 3) * 8 * 8192 + (size_t)o * 1024;
  float s = 0.f, ss = 0.f;
  for (int e = tid; e < 8192; e += 256) {
    const int bb = e >> 10, l = e & 1023;
    const float v = conv[base + (size_t)bb * 8192 + l];
    s += v;
    ss += v * v;
  }
  r1[tid] = s;
  r2[tid] = ss;
  __syncthreads();
  for (int st = 128; st > 0; st >>= 1) {
    if (tid < st) {
      r1[tid] += r1[tid + st];
      r2[tid] += r2[tid + st];
    }
    __syncthreads();
  }
  if (tid == 0) {
    const float mean = r1[0] * (1.f / 8192.f);
    const float var = r2[0] * (1.f / 8192.f) - mean * mean;
    meanw[blk] = mean;
    rstdw[blk] = rsqrtf(fmaxf(var, 0.f) + 1e-5f);
  }
  if (blk == 0 && tid == 0) {
    float d = 0.f;
    for (int i = 0; i < 64; ++i) d += Wbq[i] * Wbk[i];
    cw[0] = d * 0.125f;  // / sqrt(64)
  }
}

__device__ inline float bn_elu(float v, float mean, float rstd, float g,
                               float be) {
  const float x = (v - mean) * rstd * g + be;
  return x > 0.f ? x : expm1f(x);
}

// ---------------- kernel 4: Q gather + BN/ELU + top-1024-of-4096 -----------
__global__ __launch_bounds__(256) void qsort_kernel(
    const float* __restrict__ conv, const float* __restrict__ meanw,
    const float* __restrict__ rstdw, const float* __restrict__ bng,
    const float* __restrict__ bnb, float* __restrict__ Qt) {
  __shared__ float a[4096];
  const int tid = threadIdx.x, blk = blockIdx.x;  // blk = b'*8 + h'
  const int bp = blk >> 3, hp = blk & 7;
  const int fi = bp >> 1;
  const int bb = (bp & 1) * 4 + (hp >> 1);
  for (int j = 0; j < 4; ++j) {
    const int hh = (hp & 1) * 4 + j;
    const float mean = meanw[fi * 8 + hh], rstd = rstdw[fi * 8 + hh];
    const float g = bng[hh], be = bnb[hh];
    const float* src = conv + ((size_t)fi * 8 + bb) * 8192 + hh * 1024;
    for (int l = tid; l < 1024; l += 256)
      a[j * 1024 + l] = bn_elu(src[l], mean, rstd, g, be);
  }
  __syncthreads();
  for (int k = 2; k <= 4096; k <<= 1)
    for (int j = k >> 1; j > 0; j >>= 1) {
      for (int idx = tid; idx < 4096; idx += 256) {
        const int ixj = idx ^ j;
        if (ixj > idx) {
          const float x = a[idx], y = a[ixj];
          const bool up = (idx & k) == 0;
          if (up ? (x < y) : (x > y)) {  // descending sort
            a[idx] = y;
            a[ixj] = x;
          }
        }
      }
      __syncthreads();
    }
  for (int l = tid; l < 1024; l += 256) Qt[blk * 1024 + l] = a[l];
}

// ---------------- kernel 5: K gather + BN/ELU + mean4 + sort ----------------
__global__ __launch_bounds__(256) void ksort_kernel(
    const float* __restrict__ conv, const float* __restrict__ meanw,
    const float* __restrict__ rstdw, const float* __restrict__ bng,
    const float* __restrict__ bnb, float* __restrict__ Kt) {
  __shared__ float a[1024];
  const int tid = threadIdx.x, blk = blockIdx.x;
  const int bp = blk >> 3, hp = blk & 7;
  const int fi = bp >> 1;
  const int bb = (bp & 1) * 4 + (hp >> 1);
  for (int l = tid; l < 1024; l += 256) {
    float sum = 0.f;
    for (int j = 0; j < 4; ++j) {
      const int hh = (hp & 1) * 4 + j;
      const float mean = meanw[32 + fi * 8 + hh];
      const float rstd = rstdw[32 + fi * 8 + hh];
      const float v = conv[((size_t)(4 + fi) * 8 + bb) * 8192 + hh * 1024 + l];
      sum += bn_elu(v, mean, rstd, bng[hh], bnb[hh]);
    }
    a[l] = sum * 0.25f;
  }
  __syncthreads();
  for (int k = 2; k <= 1024; k <<= 1)
    for (int j = k >> 1; j > 0; j >>= 1) {
      for (int idx = tid; idx < 1024; idx += 256) {
        const int ixj = idx ^ j;
        if (ixj > idx) {
          const float x = a[idx], y = a[ixj];
          const bool up = (idx & k) == 0;
          if (up ? (x < y) : (x > y)) {
            a[idx] = y;
            a[ixj] = x;
          }
        }
      }
      __syncthreads();
    }
  for (int l = tid; l < 1024; l += 256) Kt[blk * 1024 + l] = a[l];
}

// ---------------- kernel 6: fused softmax(attn) write + PV (v2) -------------
// grid 512 = 64 bh x 8 q-tiles of 128 rows; 256 threads; thread owns 8q x 4d.
// E chunk [64 k][q stride 132] in LDS; V chunk [64 k][64 d] in LDS.
__global__ __launch_bounds__(256, 2) void attn2_kernel(
    const float* __restrict__ V, const float* __restrict__ Qt,
    const float* __restrict__ Kt, const float* __restrict__ cw,
    float* __restrict__ ctx, float* __restrict__ attn) {
  __shared__ float Kts[1024];
  __shared__ float sq[128], mq[128], rz[128];
  __shared__ float E[64 * 132];
  __shared__ float Vs[64 * 64];
  const int tid = threadIdx.x;
  const int b = blockIdx.x;
  // XCD swizzle: all 8 q-tiles of one bh land on the same XCD (blockIdx%8).
  const int bh = ((b & 7) << 3) | ((b >> 3) & 7);
  const int qt = b >> 6;
  const int qbase = qt * 128;
  const float cval = cw[0];
  const float* Ktg = Kt + (size_t)bh * 1024;
  for (int t = tid; t < 1024; t += 256) Kts[t] = Ktg[t];
  const float kHi = Ktg[0], kLo = Ktg[1023];  // Kt sorted descending
  if (tid < 128) {
    const float s = cval * Qt[(size_t)bh * 1024 + qbase + tid];
    sq[tid] = s;
    mq[tid] = fmaxf(s * kHi, s * kLo);
  }
  __syncthreads();
  {  // pass 1: row sums Z (2 threads per q-row)
    const int q = tid >> 1, half = tid & 1;
    const float s = sq[q], m = mq[q];
    const int kk0 = half * 512;
    float z = 0.f;
    for (int k = 0; k < 512; ++k) z += __expf(s * Kts[kk0 + k] - m);
    z += __shfl_xor(z, 1, 64);
    if (half == 0) rz[q] = 1.f / z;
  }
  __syncthreads();

  float4 acc[8];
#pragma unroll
  for (int j = 0; j < 8; ++j) acc[j] = make_float4(0.f, 0.f, 0.f, 0.f);

  const int wv = tid >> 6, lane = tid & 63;
  const int d0 = (lane & 15) * 4;
  const int q0 = (wv * 4 + (lane >> 4)) * 8;  // 0..120
  const int kkE = tid & 63;                   // E-phase k index
  const int qE0 = wv * 32;                    // E-phase q range
  const float* Vb = V + (size_t)bh * 65536;
  float* arow = attn + ((size_t)bh << 20) + (size_t)qbase * 1024;

  for (int ch = 0; ch < 16; ++ch) {
    const int k0 = ch * 64;
    // (a) issue V loads early (latency hides under E-phase)
    const float4* Vg = (const float4*)(Vb + (size_t)k0 * 64);
    float4 vst0 = Vg[tid + 0 * 256];
    float4 vst1 = Vg[tid + 1 * 256];
    float4 vst2 = Vg[tid + 2 * 256];
    float4 vst3 = Vg[tid + 3 * 256];
    // (b) E-phase: exp, normalize, write LDS + global attn
    const float kv = Kts[k0 + kkE];
#pragma unroll 8
    for (int i = 0; i < 32; ++i) {
      const int q = qE0 + i;
      const float val = __expf(fmaf(sq[q], kv, -mq[q])) * rz[q];
      E[kkE * 132 + q] = val;
      arow[(size_t)q * 1024 + k0 + kkE] = val;
    }
    // (c) commit V to LDS
    ((float4*)Vs)[tid + 0 * 256] = vst0;
    ((float4*)Vs)[tid + 1 * 256] = vst1;
    ((float4*)Vs)[tid + 2 * 256] = vst2;
    ((float4*)Vs)[tid + 3 * 256] = vst3;
    __syncthreads();
    // (d) PV: 3 LDS b128 reads (2 broadcast) per 32 FMAs
#pragma unroll 4
    for (int kk = 0; kk < 64; ++kk) {
      const float4 v4 = *(const float4*)&Vs[kk * 64 + d0];
      const float4 e0 = *(const float4*)&E[kk * 132 + q0];
      const float4 e1 = *(const float4*)&E[kk * 132 + q0 + 4];
      const float ev[8] = {e0.x, e0.y, e0.z, e0.w, e1.x, e1.y, e1.z, e1.w};
#pragma unroll
      for (int j = 0; j < 8; ++j) {
        acc[j].x = fmaf(ev[j], v4.x, acc[j].x);
        acc[j].y = fmaf(ev[j], v4.y, acc[j].y);
        acc[j].z = fmaf(ev[j], v4.z, acc[j].z);
        acc[j].w = fmaf(ev[j], v4.w, acc[j].w);
      }
    }
    __syncthreads();
  }
#pragma unroll
  for (int j = 0; j < 8; ++j)
    *(float4*)&ctx[((size_t)bh * 1024 + qbase + q0 + j) * 64 + d0] = acc[j];
}

}  // namespace

extern "C" void kernel_launch(void* const* d_in, const int* in_sizes, int n_in,
                              void* d_out, int out_size, void* d_ws,
                              size_t ws_size, hipStream_t stream) {
  const float* Q = (const float*)d_in[0];
  const float* K = (const float*)d_in[1];
  const float* V = (const float*)d_in[2];
  const float* Wpq = (const float*)d_in[3];
  const float* Wbq = (const float*)d_in[4];
  const float* Wbk = (const float*)d_in[5];
  const float* bng = (const float*)d_in[6];
  const float* bnb = (const float*)d_in[7];
  // d_in[8] = attn_mask (all ones, unused)
  const float* cqw[4] = {(const float*)d_in[9], (const float*)d_in[13],
                         (const float*)d_in[17], (const float*)d_in[21]};
  const float* cqb[4] = {(const float*)d_in[10], (const float*)d_in[14],
                         (const float*)d_in[18], (const float*)d_in[22]};
  const float* ckw[4] = {(const float*)d_in[11], (const float*)d_in[15],
                         (const float*)d_in[19], (const float*)d_in[23]};
  const float* ckb[4] = {(const float*)d_in[12], (const float*)d_in[16],
                         (const float*)d_in[20], (const float*)d_in[24]};

  float* ws = (float*)d_ws;
  float* proj = ws + PROJ_OFF;
  float* conv = ws + CONV_OFF;
  float* meanw = ws + MEAN_OFF;
  float* rstdw = ws + RSTD_OFF;
  float* cw = ws + C_OFF;
  float* Qtp = ws + QT_OFF;
  float* Ktp = ws + KT_OFF;
  float* ctx = (float*)d_out;
  float* attn = ctx + (size_t)8 * 8 * 1024 * 64;

  proj_kernel<<<512, 256, 0, stream>>>(Q, K, Wpq, proj);
  conv_kernel<<<64, 256, 0, stream>>>(
      proj, cqw[0], cqb[0], cqw[1], cqb[1], cqw[2], cqb[2], cqw[3], cqb[3],
      ckw[0], ckb[0], ckw[1], ckb[1], ckw[2], ckb[2], ckw[3], ckb[3], conv);
  stats_kernel<<<64, 256, 0, stream>>>(conv, Wbq, Wbk, meanw, rstdw, cw);
  qsort_kernel<<<64, 256, 0, stream>>>(conv, meanw, rstdw, bng, bnb, Qtp);
  ksort_kernel<<<64, 256, 0, stream>>>(conv, meanw, rstdw, bng, bnb, Ktp);
  attn2_kernel<<<512, 256, 0, stream>>>(V, Qtp, Ktp, cw, ctx, attn);
}

// Round 3
// 257.495 us; speedup vs baseline: 2.5957x; 1.8280x over previous
//
#include <hip/hip_runtime.h>
#include <math.h>

// ---------------- workspace layout (float offsets) ----------------
// proj  [2][8][8][1024]            @ 0        (131072)
// conv  [2][4][8][8][1024]         @ 131072   (524288)
// mean  [2][4][8]                  @ 655360   (64)
// rstd  [2][4][8]                  @ 655424   (64)
// c     [1]                        @ 655488
// Qt    [64][1024]                 @ 655616   (65536)
// Kt    [64][1024]                 @ 721152   (65536)
// Q chunk scratch lives in d_out's attn region (overwritten by attn2 later).
namespace {
constexpr int PROJ_OFF = 0;
constexpr int CONV_OFF = 131072;
constexpr int MEAN_OFF = 655360;
constexpr int RSTD_OFF = 655424;
constexpr int C_OFF    = 655488;
constexpr int QT_OFF   = 655616;
constexpr int KT_OFF   = 721152;

// ---------------- kernel 1: projection q/k = X . W_pq (1 row/thread) -------
__global__ __launch_bounds__(256) void proj_kernel(
    const float* __restrict__ Q, const float* __restrict__ K,
    const float* __restrict__ Wpq, float* __restrict__ proj) {
  __shared__ float wsh[64];
  const int tid = threadIdx.x;
  if (tid < 64) wsh[tid] = Wpq[tid];
  __syncthreads();
  const int row = blockIdx.x * 256 + tid;  // 0..131071
  const float* src = (row < 65536) ? (Q + (size_t)row * 64)
                                   : (K + (size_t)(row - 65536) * 64);
  float acc = 0.f;
#pragma unroll
  for (int j = 0; j < 16; ++j) {
    const float4 v = *(const float4*)(src + j * 4);
    acc = fmaf(v.x, wsh[j * 4 + 0], acc);
    acc = fmaf(v.y, wsh[j * 4 + 1], acc);
    acc = fmaf(v.z, wsh[j * 4 + 2], acc);
    acc = fmaf(v.w, wsh[j * 4 + 3], acc);
  }
  proj[row] = acc;
}

// ---------------- kernel 2: conv1d (4 filters x 2 paths) ----------------
template <int F>
__device__ void conv_body(const float* __restrict__ xs,
                          const float* __restrict__ wsm,
                          const float* __restrict__ bsm,
                          float* __restrict__ outp, int tid) {
  constexpr int pad = (F - 1) / 2;
  for (int e = tid; e < 8192; e += 256) {
    const int o = e >> 10, l = e & 1023;
    float acc = bsm[o];
#pragma unroll
    for (int c = 0; c < 8; ++c) {
      const float* wrow = &wsm[(o * 8 + c) * F];
#pragma unroll
      for (int f = 0; f < F; ++f) {
        const int pos = l + f - pad;
        if (pos >= 0 && pos < 1024) acc = fmaf(xs[c * 1024 + pos], wrow[f], acc);
      }
    }
    outp[e] = acc;
  }
}

__global__ __launch_bounds__(256) void conv_kernel(
    const float* __restrict__ proj,
    const float* __restrict__ wq0, const float* __restrict__ bq0,
    const float* __restrict__ wq1, const float* __restrict__ bq1,
    const float* __restrict__ wq2, const float* __restrict__ bq2,
    const float* __restrict__ wq3, const float* __restrict__ bq3,
    const float* __restrict__ wk0, const float* __restrict__ bk0,
    const float* __restrict__ wk1, const float* __restrict__ bk1,
    const float* __restrict__ wk2, const float* __restrict__ bk2,
    const float* __restrict__ wk3, const float* __restrict__ bk3,
    float* __restrict__ conv) {
  __shared__ float xs[8 * 1024];
  __shared__ float wsm[8 * 8 * 9];
  __shared__ float bsm[8];
  const int tid = threadIdx.x;
  const int blk = blockIdx.x;  // 64 blocks: (path, filt, batch)
  const int path = blk >> 5, fi = (blk >> 3) & 3, bb = blk & 7;
  const int F = (0x9731 >> (fi * 4)) & 0xF;  // 1,3,7,9
  const float* wp;
  const float* bp;
  if (path == 0) {
    wp = fi == 0 ? wq0 : fi == 1 ? wq1 : fi == 2 ? wq2 : wq3;
    bp = fi == 0 ? bq0 : fi == 1 ? bq1 : fi == 2 ? bq2 : bq3;
  } else {
    wp = fi == 0 ? wk0 : fi == 1 ? wk1 : fi == 2 ? wk2 : wk3;
    bp = fi == 0 ? bk0 : fi == 1 ? bk1 : fi == 2 ? bk2 : bk3;
  }
  for (int e = tid; e < 8192; e += 256)
    xs[e] = proj[path * 65536 + bb * 8192 + e];
  for (int e = tid; e < 64 * F; e += 256) wsm[e] = wp[e];
  if (tid < 8) bsm[tid] = bp[tid];
  __syncthreads();
  float* outp = conv + ((size_t)(path * 4 + fi) * 8 + bb) * 8192;
  if (fi == 0)
    conv_body<1>(xs, wsm, bsm, outp, tid);
  else if (fi == 1)
    conv_body<3>(xs, wsm, bsm, outp, tid);
  else if (fi == 2)
    conv_body<7>(xs, wsm, bsm, outp, tid);
  else
    conv_body<9>(xs, wsm, bsm, outp, tid);
}

// ---------------- kernel 3: BN batch stats + scalar c ----------------
__global__ __launch_bounds__(256) void stats_kernel(
    const float* __restrict__ conv,
    const float* __restrict__ Wbq, const float* __restrict__ Wbk,
    float* __restrict__ meanw, float* __restrict__ rstdw,
    float* __restrict__ cw) {
  __shared__ float r1[256], r2[256];
  const int tid = threadIdx.x, blk = blockIdx.x;  // blk = path*32+fi*8+o
  const int o = blk & 7;
  const size_t base = (size_t)(blk >> 3) * 8 * 8192 + (size_t)o * 1024;
  float s = 0.f, ss = 0.f;
  for (int e = tid; e < 8192; e += 256) {
    const int bb = e >> 10, l = e & 1023;
    const float v = conv[base + (size_t)bb * 8192 + l];
    s += v;
    ss += v * v;
  }
  r1[tid] = s;
  r2[tid] = ss;
  __syncthreads();
  for (int st = 128; st > 0; st >>= 1) {
    if (tid < st) {
      r1[tid] += r1[tid + st];
      r2[tid] += r2[tid + st];
    }
    __syncthreads();
  }
  if (tid == 0) {
    const float mean = r1[0] * (1.f / 8192.f);
    const float var = r2[0] * (1.f / 8192.f) - mean * mean;
    meanw[blk] = mean;
    rstdw[blk] = rsqrtf(fmaxf(var, 0.f) + 1e-5f);
  }
  if (blk == 0 && tid == 0) {
    float d = 0.f;
    for (int i = 0; i < 64; ++i) d += Wbq[i] * Wbk[i];
    cw[0] = d * 0.125f;  // / sqrt(64)
  }
}

__device__ inline float bn_elu(float v, float mean, float rstd, float g,
                               float be) {
  const float x = (v - mean) * rstd * g + be;
  return x > 0.f ? x : expm1f(x);
}

// ============ register/shuffle bitonic sort machinery ============
// 256 threads, 4 elems/thread (g = 4t+e), descending order.
// up==true => keep larger value at lower index.
__device__ inline void cswap(float& a, float& b, bool up) {
  const float mx = fmaxf(a, b), mn = fminf(a, b);
  a = up ? mx : mn;
  b = up ? mn : mx;
}

// comparator distance j = 4*m, partner lane = lane ^ m (m <= 32: in-wave)
__device__ inline void shfl_pass(float v[4], int t, int m, bool up) {
  const bool keepmax = (up == ((t & m) == 0));
#pragma unroll
  for (int e = 0; e < 4; ++e) {
    const float p = __shfl_xor(v[e], m, 64);
    v[e] = keepmax ? fmaxf(v[e], p) : fminf(v[e], p);
  }
}

// comparator distance j = 4*jq, jq in {64,128}: cross-wave via LDS
__device__ inline void lds_pass(float v[4], float* s, int t, int jq, bool up) {
  *(float4*)&s[4 * t] = make_float4(v[0], v[1], v[2], v[3]);
  __syncthreads();
  const int pt = t ^ jq;
  const bool keepmax = (up == ((t & jq) == 0));
  const float4 p = *(const float4*)&s[4 * pt];
  v[0] = keepmax ? fmaxf(v[0], p.x) : fminf(v[0], p.x);
  v[1] = keepmax ? fmaxf(v[1], p.y) : fminf(v[1], p.y);
  v[2] = keepmax ? fmaxf(v[2], p.z) : fminf(v[2], p.z);
  v[3] = keepmax ? fmaxf(v[3], p.w) : fminf(v[3], p.w);
  __syncthreads();
}

// passes j=128..1 (tail of a k-stage)
__device__ inline void reg_tail(float v[4], int t, bool up) {
#pragma unroll
  for (int m = 32; m >= 1; m >>= 1) shfl_pass(v, t, m, up);
  cswap(v[0], v[2], up);
  cswap(v[1], v[3], up);
  cswap(v[0], v[1], up);
  cswap(v[2], v[3], up);
}

__device__ inline void sort1024(float v[4], float* s, int t) {
  cswap(v[0], v[1], true);   // k=2: pair(0,1) up
  cswap(v[2], v[3], false);  // k=2: pair(2,3) down
#pragma unroll
  for (int k = 4; k <= 256; k <<= 1) {
    const bool up = ((t & (k >> 2)) == 0);
    for (int m = k >> 3; m >= 1; m >>= 1) shfl_pass(v, t, m, up);
    cswap(v[0], v[2], up);
    cswap(v[1], v[3], up);
    cswap(v[0], v[1], up);
    cswap(v[2], v[3], up);
  }
  {  // k=512: j=256 via LDS, then j<=128 in registers
    const bool up = ((t & 128) == 0);
    lds_pass(v, s, t, 64, up);
    reg_tail(v, t, up);
  }
  // k=1024 (final, up=true everywhere): j=512,256 via LDS, then tail
  lds_pass(v, s, t, 128, true);
  lds_pass(v, s, t, 64, true);
  reg_tail(v, t, true);
}

// bitonic -> descending merge of 1024-seq held in v[4]
__device__ inline void bmerge1024(float v[4], float* s, int t) {
  lds_pass(v, s, t, 128, true);  // j=512
  lds_pass(v, s, t, 64, true);   // j=256
  reg_tail(v, t, true);          // j=128..1
}

// ---------------- kernel 4: per-chunk BN/ELU + sort ----------------
// grid 320: blk<256 -> Q chunk (row=blk>>2, chunk=blk&3) -> chunks[]
//           blk>=256 -> K row (mean of 4) -> Kt[] (final)
__global__ __launch_bounds__(256) void chunksort_kernel(
    const float* __restrict__ conv, const float* __restrict__ meanw,
    const float* __restrict__ rstdw, const float* __restrict__ bng,
    const float* __restrict__ bnb, float* __restrict__ chunks,
    float* __restrict__ Kt) {
  __shared__ float s[1024];
  const int t = threadIdx.x, blk = blockIdx.x;
  float v[4];
  if (blk < 256) {
    const int row = blk >> 2, jc = blk & 3;
    const int bp = row >> 3, hp = row & 7;
    const int fi = bp >> 1, bb = (bp & 1) * 4 + (hp >> 1);
    const int hh = (hp & 1) * 4 + jc;
    const float mean = meanw[fi * 8 + hh], rstd = rstdw[fi * 8 + hh];
    const float g = bng[hh], be = bnb[hh];
    const float4 x = *(const float4*)&conv[(size_t)(fi * 8 + bb) * 8192 +
                                           hh * 1024 + 4 * t];
    v[0] = bn_elu(x.x, mean, rstd, g, be);
    v[1] = bn_elu(x.y, mean, rstd, g, be);
    v[2] = bn_elu(x.z, mean, rstd, g, be);
    v[3] = bn_elu(x.w, mean, rstd, g, be);
    sort1024(v, s, t);
    *(float4*)&chunks[(size_t)blk * 1024 + 4 * t] =
        make_float4(v[0], v[1], v[2], v[3]);
  } else {
    const int row = blk - 256;
    const int bp = row >> 3, hp = row & 7;
    const int fi = bp >> 1, bb = (bp & 1) * 4 + (hp >> 1);
    float sum0 = 0.f, sum1 = 0.f, sum2 = 0.f, sum3 = 0.f;
#pragma unroll
    for (int j = 0; j < 4; ++j) {
      const int hh = (hp & 1) * 4 + j;
      const float mean = meanw[32 + fi * 8 + hh];
      const float rstd = rstdw[32 + fi * 8 + hh];
      const float g = bng[hh], be = bnb[hh];
      const float4 x = *(const float4*)&conv[(size_t)(4 + fi) * 64 * 1024 +
                                             (size_t)bb * 8192 + hh * 1024 +
                                             4 * t];
      sum0 += bn_elu(x.x, mean, rstd, g, be);
      sum1 += bn_elu(x.y, mean, rstd, g, be);
      sum2 += bn_elu(x.z, mean, rstd, g, be);
      sum3 += bn_elu(x.w, mean, rstd, g, be);
    }
    v[0] = sum0 * 0.25f;
    v[1] = sum1 * 0.25f;
    v[2] = sum2 * 0.25f;
    v[3] = sum3 * 0.25f;
    sort1024(v, s, t);
    *(float4*)&Kt[(size_t)row * 1024 + 4 * t] =
        make_float4(v[0], v[1], v[2], v[3]);
  }
}

// ---------------- kernel 5: merge 4 sorted chunks -> top-1024 sorted --------
__global__ __launch_bounds__(256) void qmerge_kernel(
    const float* __restrict__ chunks, float* __restrict__ Qt) {
  __shared__ float s1[1024];
  __shared__ float s2[1024];
  const int t = threadIdx.x, row = blockIdx.x;
  const float* cb = chunks + (size_t)row * 4096;
  float a[4], b[4];
  {
    const float4 a0 = *(const float4*)&cb[4 * t];
    const float4 b0 = *(const float4*)&cb[2048 + 4 * t];
    float r1[4], r3[4];
#pragma unroll
    for (int e = 0; e < 4; ++e) {
      r1[e] = cb[1024 + 1023 - (4 * t + e)];
      r3[e] = cb[3072 + 1023 - (4 * t + e)];
    }
    a[0] = fmaxf(a0.x, r1[0]);
    a[1] = fmaxf(a0.y, r1[1]);
    a[2] = fmaxf(a0.z, r1[2]);
    a[3] = fmaxf(a0.w, r1[3]);
    b[0] = fmaxf(b0.x, r3[0]);
    b[1] = fmaxf(b0.y, r3[1]);
    b[2] = fmaxf(b0.z, r3[2]);
    b[3] = fmaxf(b0.w, r3[3]);
  }
  bmerge1024(a, s1, t);  // top-1024 of chunks 0,1 sorted desc
  bmerge1024(b, s2, t);  // top-1024 of chunks 2,3 sorted desc
  // final: c = max(a[g], b[1023-g]) -> bitonic -> merge
  *(float4*)&s2[4 * t] = make_float4(b[0], b[1], b[2], b[3]);
  __syncthreads();
#pragma unroll
  for (int e = 0; e < 4; ++e) a[e] = fmaxf(a[e], s2[1023 - (4 * t + e)]);
  bmerge1024(a, s1, t);
  *(float4*)&Qt[(size_t)row * 1024 + 4 * t] =
      make_float4(a[0], a[1], a[2], a[3]);
}

// ---------------- kernel 6: fused softmax(attn) write + PV (v2) -------------
// grid 512 = 64 bh x 8 q-tiles of 128 rows; 256 threads; thread owns 8q x 4d.
// E chunk [64 k][q stride 132] in LDS; V chunk [64 k][64 d] in LDS.
__global__ __launch_bounds__(256, 2) void attn2_kernel(
    const float* __restrict__ V, const float* __restrict__ Qt,
    const float* __restrict__ Kt, const float* __restrict__ cw,
    float* __restrict__ ctx, float* __restrict__ attn) {
  __shared__ float Kts[1024];
  __shared__ float sq[128], mq[128], rz[128];
  __shared__ float E[64 * 132];
  __shared__ float Vs[64 * 64];
  const int tid = threadIdx.x;
  const int b = blockIdx.x;
  // XCD swizzle: all 8 q-tiles of one bh land on the same XCD (blockIdx%8).
  const int bh = ((b & 7) << 3) | ((b >> 3) & 7);
  const int qt = b >> 6;
  const int qbase = qt * 128;
  const float cval = cw[0];
  const float* Ktg = Kt + (size_t)bh * 1024;
  for (int t = tid; t < 1024; t += 256) Kts[t] = Ktg[t];
  const float kHi = Ktg[0], kLo = Ktg[1023];  // Kt sorted descending
  if (tid < 128) {
    const float s = cval * Qt[(size_t)bh * 1024 + qbase + tid];
    sq[tid] = s;
    mq[tid] = fmaxf(s * kHi, s * kLo);
  }
  __syncthreads();
  {  // pass 1: row sums Z (2 threads per q-row)
    const int q = tid >> 1, half = tid & 1;
    const float s = sq[q], m = mq[q];
    const int kk0 = half * 512;
    float z = 0.f;
    for (int k = 0; k < 512; ++k) z += __expf(s * Kts[kk0 + k] - m);
    z += __shfl_xor(z, 1, 64);
    if (half == 0) rz[q] = 1.f / z;
  }
  __syncthreads();

  float4 acc[8];
#pragma unroll
  for (int j = 0; j < 8; ++j) acc[j] = make_float4(0.f, 0.f, 0.f, 0.f);

  const int wv = tid >> 6, lane = tid & 63;
  const int d0 = (lane & 15) * 4;
  const int q0 = (wv * 4 + (lane >> 4)) * 8;  // 0..120
  const int kkE = tid & 63;                   // E-phase k index
  const int qE0 = wv * 32;                    // E-phase q range
  const float* Vb = V + (size_t)bh * 65536;
  float* arow = attn + ((size_t)bh << 20) + (size_t)qbase * 1024;

  for (int ch = 0; ch < 16; ++ch) {
    const int k0 = ch * 64;
    // (a) issue V loads early (latency hides under E-phase)
    const float4* Vg = (const float4*)(Vb + (size_t)k0 * 64);
    float4 vst0 = Vg[tid + 0 * 256];
    float4 vst1 = Vg[tid + 1 * 256];
    float4 vst2 = Vg[tid + 2 * 256];
    float4 vst3 = Vg[tid + 3 * 256];
    // (b) E-phase: exp, normalize, write LDS + global attn
    const float kv = Kts[k0 + kkE];
#pragma unroll 8
    for (int i = 0; i < 32; ++i) {
      const int q = qE0 + i;
      const float val = __expf(fmaf(sq[q], kv, -mq[q])) * rz[q];
      E[kkE * 132 + q] = val;
      arow[(size_t)q * 1024 + k0 + kkE] = val;
    }
    // (c) commit V to LDS
    ((float4*)Vs)[tid + 0 * 256] = vst0;
    ((float4*)Vs)[tid + 1 * 256] = vst1;
    ((float4*)Vs)[tid + 2 * 256] = vst2;
    ((float4*)Vs)[tid + 3 * 256] = vst3;
    __syncthreads();
    // (d) PV: 3 LDS b128 reads (2 broadcast) per 32 FMAs
#pragma unroll 4
    for (int kk = 0; kk < 64; ++kk) {
      const float4 v4 = *(const float4*)&Vs[kk * 64 + d0];
      const float4 e0 = *(const float4*)&E[kk * 132 + q0];
      const float4 e1 = *(const float4*)&E[kk * 132 + q0 + 4];
      const float ev[8] = {e0.x, e0.y, e0.z, e0.w, e1.x, e1.y, e1.z, e1.w};
#pragma unroll
      for (int j = 0; j < 8; ++j) {
        acc[j].x = fmaf(ev[j], v4.x, acc[j].x);
        acc[j].y = fmaf(ev[j], v4.y, acc[j].y);
        acc[j].z = fmaf(ev[j], v4.z, acc[j].z);
        acc[j].w = fmaf(ev[j], v4.w, acc[j].w);
      }
    }
    __syncthreads();
  }
#pragma unroll
  for (int j = 0; j < 8; ++j)
    *(float4*)&ctx[((size_t)bh * 1024 + qbase + q0 + j) * 64 + d0] = acc[j];
}

}  // namespace

extern "C" void kernel_launch(void* const* d_in, const int* in_sizes, int n_in,
                              void* d_out, int out_size, void* d_ws,
                              size_t ws_size, hipStream_t stream) {
  const float* Q = (const float*)d_in[0];
  const float* K = (const float*)d_in[1];
  const float* V = (const float*)d_in[2];
  const float* Wpq = (const float*)d_in[3];
  const float* Wbq = (const float*)d_in[4];
  const float* Wbk = (const float*)d_in[5];
  const float* bng = (const float*)d_in[6];
  const float* bnb = (const float*)d_in[7];
  // d_in[8] = attn_mask (all ones, unused)
  const float* cqw[4] = {(const float*)d_in[9], (const float*)d_in[13],
                         (const float*)d_in[17], (const float*)d_in[21]};
  const float* cqb[4] = {(const float*)d_in[10], (const float*)d_in[14],
                         (const float*)d_in[18], (const float*)d_in[22]};
  const float* ckw[4] = {(const float*)d_in[11], (const float*)d_in[15],
                         (const float*)d_in[19], (const float*)d_in[23]};
  const float* ckb[4] = {(const float*)d_in[12], (const float*)d_in[16],
                         (const float*)d_in[20], (const float*)d_in[24]};

  float* ws = (float*)d_ws;
  float* proj = ws + PROJ_OFF;
  float* conv = ws + CONV_OFF;
  float* meanw = ws + MEAN_OFF;
  float* rstdw = ws + RSTD_OFF;
  float* cw = ws + C_OFF;
  float* Qtp = ws + QT_OFF;
  float* Ktp = ws + KT_OFF;
  float* ctx = (float*)d_out;
  float* attn = ctx + (size_t)8 * 8 * 1024 * 64;
  // Q chunk scratch: reuse the attn output region (fully overwritten by
  // attn2_kernel afterwards, so timed-replay re-validation stays correct).
  float* chunks = attn;  // [64][4][1024] floats

  proj_kernel<<<512, 256, 0, stream>>>(Q, K, Wpq, proj);
  conv_kernel<<<64, 256, 0, stream>>>(
      proj, cqw[0], cqb[0], cqw[1], cqb[1], cqw[2], cqb[2], cqw[3], cqb[3],
      ckw[0], ckb[0], ckw[1], ckb[1], ckw[2], ckb[2], ckw[3], ckb[3], conv);
  stats_kernel<<<64, 256, 0, stream>>>(conv, Wbq, Wbk, meanw, rstdw, cw);
  chunksort_kernel<<<320, 256, 0, stream>>>(conv, meanw, rstdw, bng, bnb,
                                            chunks, Ktp);
  qmerge_kernel<<<64, 256, 0, stream>>>(chunks, Qtp);
  attn2_kernel<<<512, 256, 0, stream>>>(V, Qtp, Ktp, cw, ctx, attn);
}

// Round 4
// 204.694 us; speedup vs baseline: 3.2652x; 1.2579x over previous
//
#include <hip/hip_runtime.h>
#include <math.h>

// ---------------- workspace layout (float offsets) ----------------
// proj  [2][8][8][1024]            @ 0        (131072)
// conv  [2][4][8][8][1024]         @ 131072   (524288)
// mean  [2][4][8]                  @ 655360   (64)
// rstd  [2][4][8]                  @ 655424   (64)
// c     [1]                        @ 655488
// Qt    [64][1024]                 @ 655616   (65536)
// Kt    [64][1024]                 @ 721152   (65536)
// Q chunk scratch lives in d_out's attn region (overwritten by attn3 later).
namespace {
constexpr int PROJ_OFF = 0;
constexpr int CONV_OFF = 131072;
constexpr int MEAN_OFF = 655360;
constexpr int RSTD_OFF = 655424;
constexpr int C_OFF    = 655488;
constexpr int QT_OFF   = 655616;
constexpr int KT_OFF   = 721152;

typedef short bf16x8 __attribute__((ext_vector_type(8)));
typedef float f32x4 __attribute__((ext_vector_type(4)));

__device__ inline short f2bf(float f) {
  union { float f; unsigned u; } c;
  c.f = f;
  const unsigned r = (c.u + 0x7fffu + ((c.u >> 16) & 1u)) >> 16;
  return (short)r;
}
__device__ inline float bf2f(short b) {
  union { unsigned u; float f; } c;
  c.u = ((unsigned)(unsigned short)b) << 16;
  return c.f;
}

// ---------------- kernel 1: projection q/k = X . W_pq (1 row/thread) -------
__global__ __launch_bounds__(256) void proj_kernel(
    const float* __restrict__ Q, const float* __restrict__ K,
    const float* __restrict__ Wpq, float* __restrict__ proj) {
  __shared__ float wsh[64];
  const int tid = threadIdx.x;
  if (tid < 64) wsh[tid] = Wpq[tid];
  __syncthreads();
  const int row = blockIdx.x * 256 + tid;  // 0..131071
  const float* src = (row < 65536) ? (Q + (size_t)row * 64)
                                   : (K + (size_t)(row - 65536) * 64);
  float acc = 0.f;
#pragma unroll
  for (int j = 0; j < 16; ++j) {
    const float4 v = *(const float4*)(src + j * 4);
    acc = fmaf(v.x, wsh[j * 4 + 0], acc);
    acc = fmaf(v.y, wsh[j * 4 + 1], acc);
    acc = fmaf(v.z, wsh[j * 4 + 2], acc);
    acc = fmaf(v.w, wsh[j * 4 + 3], acc);
  }
  proj[row] = acc;
}

// ---------------- kernel 2: conv1d (4 filters x 2 paths) ----------------
template <int F>
__device__ void conv_body(const float* __restrict__ xs,
                          const float* __restrict__ wsm,
                          const float* __restrict__ bsm,
                          float* __restrict__ outp, int tid) {
  constexpr int pad = (F - 1) / 2;
  for (int e = tid; e < 8192; e += 256) {
    const int o = e >> 10, l = e & 1023;
    float acc = bsm[o];
#pragma unroll
    for (int c = 0; c < 8; ++c) {
      const float* wrow = &wsm[(o * 8 + c) * F];
#pragma unroll
      for (int f = 0; f < F; ++f) {
        const int pos = l + f - pad;
        if (pos >= 0 && pos < 1024) acc = fmaf(xs[c * 1024 + pos], wrow[f], acc);
      }
    }
    outp[e] = acc;
  }
}

__global__ __launch_bounds__(256) void conv_kernel(
    const float* __restrict__ proj,
    const float* __restrict__ wq0, const float* __restrict__ bq0,
    const float* __restrict__ wq1, const float* __restrict__ bq1,
    const float* __restrict__ wq2, const float* __restrict__ bq2,
    const float* __restrict__ wq3, const float* __restrict__ bq3,
    const float* __restrict__ wk0, const float* __restrict__ bk0,
    const float* __restrict__ wk1, const float* __restrict__ bk1,
    const float* __restrict__ wk2, const float* __restrict__ bk2,
    const float* __restrict__ wk3, const float* __restrict__ bk3,
    float* __restrict__ conv) {
  __shared__ float xs[8 * 1024];
  __shared__ float wsm[8 * 8 * 9];
  __shared__ float bsm[8];
  const int tid = threadIdx.x;
  const int blk = blockIdx.x;  // 64 blocks: (path, filt, batch)
  const int path = blk >> 5, fi = (blk >> 3) & 3, bb = blk & 7;
  const int F = (0x9731 >> (fi * 4)) & 0xF;  // 1,3,7,9
  const float* wp;
  const float* bp;
  if (path == 0) {
    wp = fi == 0 ? wq0 : fi == 1 ? wq1 : fi == 2 ? wq2 : wq3;
    bp = fi == 0 ? bq0 : fi == 1 ? bq1 : fi == 2 ? bq2 : bq3;
  } else {
    wp = fi == 0 ? wk0 : fi == 1 ? wk1 : fi == 2 ? wk2 : wk3;
    bp = fi == 0 ? bk0 : fi == 1 ? bk1 : fi == 2 ? bk2 : bk3;
  }
  for (int e = tid; e < 8192; e += 256)
    xs[e] = proj[path * 65536 + bb * 8192 + e];
  for (int e = tid; e < 64 * F; e += 256) wsm[e] = wp[e];
  if (tid < 8) bsm[tid] = bp[tid];
  __syncthreads();
  float* outp = conv + ((size_t)(path * 4 + fi) * 8 + bb) * 8192;
  if (fi == 0)
    conv_body<1>(xs, wsm, bsm, outp, tid);
  else if (fi == 1)
    conv_body<3>(xs, wsm, bsm, outp, tid);
  else if (fi == 2)
    conv_body<7>(xs, wsm, bsm, outp, tid);
  else
    conv_body<9>(xs, wsm, bsm, outp, tid);
}

// ---------------- kernel 3: BN batch stats + scalar c ----------------
__global__ __launch_bounds__(256) void stats_kernel(
    const float* __restrict__ conv,
    const float* __restrict__ Wbq, const float* __restrict__ Wbk,
    float* __restrict__ meanw, float* __restrict__ rstdw,
    float* __restrict__ cw) {
  __shared__ float r1[256], r2[256];
  const int tid = threadIdx.x, blk = blockIdx.x;  // blk = path*32+fi*8+o
  const int o = blk & 7;
  const size_t base = (size_t)(blk >> 3) * 8 * 8192 + (size_t)o * 1024;
  float s = 0.f, ss = 0.f;
  for (int e = tid; e < 8192; e += 256) {
    const int bb = e >> 10, l = e & 1023;
    const float v = conv[base + (size_t)bb * 8192 + l];
    s += v;
    ss += v * v;
  }
  r1[tid] = s;
  r2[tid] = ss;
  __syncthreads();
  for (int st = 128; st > 0; st >>= 1) {
    if (tid < st) {
      r1[tid] += r1[tid + st];
      r2[tid] += r2[tid + st];
    }
    __syncthreads();
  }
  if (tid == 0) {
    const float mean = r1[0] * (1.f / 8192.f);
    const float var = r2[0] * (1.f / 8192.f) - mean * mean;
    meanw[blk] = mean;
    rstdw[blk] = rsqrtf(fmaxf(var, 0.f) + 1e-5f);
  }
  if (blk == 0 && tid == 0) {
    float d = 0.f;
    for (int i = 0; i < 64; ++i) d += Wbq[i] * Wbk[i];
    cw[0] = d * 0.125f;  // / sqrt(64)
  }
}

__device__ inline float bn_elu(float v, float mean, float rstd, float g,
                               float be) {
  const float x = (v - mean) * rstd * g + be;
  return x > 0.f ? x : expm1f(x);
}

// ============ register/shuffle bitonic sort machinery ============
__device__ inline void cswap(float& a, float& b, bool up) {
  const float mx = fmaxf(a, b), mn = fminf(a, b);
  a = up ? mx : mn;
  b = up ? mn : mx;
}

__device__ inline void shfl_pass(float v[4], int t, int m, bool up) {
  const bool keepmax = (up == ((t & m) == 0));
#pragma unroll
  for (int e = 0; e < 4; ++e) {
    const float p = __shfl_xor(v[e], m, 64);
    v[e] = keepmax ? fmaxf(v[e], p) : fminf(v[e], p);
  }
}

__device__ inline void lds_pass(float v[4], float* s, int t, int jq, bool up) {
  *(float4*)&s[4 * t] = make_float4(v[0], v[1], v[2], v[3]);
  __syncthreads();
  const int pt = t ^ jq;
  const bool keepmax = (up == ((t & jq) == 0));
  const float4 p = *(const float4*)&s[4 * pt];
  v[0] = keepmax ? fmaxf(v[0], p.x) : fminf(v[0], p.x);
  v[1] = keepmax ? fmaxf(v[1], p.y) : fminf(v[1], p.y);
  v[2] = keepmax ? fmaxf(v[2], p.z) : fminf(v[2], p.z);
  v[3] = keepmax ? fmaxf(v[3], p.w) : fminf(v[3], p.w);
  __syncthreads();
}

__device__ inline void reg_tail(float v[4], int t, bool up) {
#pragma unroll
  for (int m = 32; m >= 1; m >>= 1) shfl_pass(v, t, m, up);
  cswap(v[0], v[2], up);
  cswap(v[1], v[3], up);
  cswap(v[0], v[1], up);
  cswap(v[2], v[3], up);
}

__device__ inline void sort1024(float v[4], float* s, int t) {
  cswap(v[0], v[1], true);
  cswap(v[2], v[3], false);
#pragma unroll
  for (int k = 4; k <= 256; k <<= 1) {
    const bool up = ((t & (k >> 2)) == 0);
    for (int m = k >> 3; m >= 1; m >>= 1) shfl_pass(v, t, m, up);
    cswap(v[0], v[2], up);
    cswap(v[1], v[3], up);
    cswap(v[0], v[1], up);
    cswap(v[2], v[3], up);
  }
  {
    const bool up = ((t & 128) == 0);
    lds_pass(v, s, t, 64, up);
    reg_tail(v, t, up);
  }
  lds_pass(v, s, t, 128, true);
  lds_pass(v, s, t, 64, true);
  reg_tail(v, t, true);
}

__device__ inline void bmerge1024(float v[4], float* s, int t) {
  lds_pass(v, s, t, 128, true);
  lds_pass(v, s, t, 64, true);
  reg_tail(v, t, true);
}

// ---------------- kernel 4: per-chunk BN/ELU + sort ----------------
__global__ __launch_bounds__(256) void chunksort_kernel(
    const float* __restrict__ conv, const float* __restrict__ meanw,
    const float* __restrict__ rstdw, const float* __restrict__ bng,
    const float* __restrict__ bnb, float* __restrict__ chunks,
    float* __restrict__ Kt) {
  __shared__ float s[1024];
  const int t = threadIdx.x, blk = blockIdx.x;
  float v[4];
  if (blk < 256) {
    const int row = blk >> 2, jc = blk & 3;
    const int bp = row >> 3, hp = row & 7;
    const int fi = bp >> 1, bb = (bp & 1) * 4 + (hp >> 1);
    const int hh = (hp & 1) * 4 + jc;
    const float mean = meanw[fi * 8 + hh], rstd = rstdw[fi * 8 + hh];
    const float g = bng[hh], be = bnb[hh];
    const float4 x = *(const float4*)&conv[(size_t)(fi * 8 + bb) * 8192 +
                                           hh * 1024 + 4 * t];
    v[0] = bn_elu(x.x, mean, rstd, g, be);
    v[1] = bn_elu(x.y, mean, rstd, g, be);
    v[2] = bn_elu(x.z, mean, rstd, g, be);
    v[3] = bn_elu(x.w, mean, rstd, g, be);
    sort1024(v, s, t);
    *(float4*)&chunks[(size_t)blk * 1024 + 4 * t] =
        make_float4(v[0], v[1], v[2], v[3]);
  } else {
    const int row = blk - 256;
    const int bp = row >> 3, hp = row & 7;
    const int fi = bp >> 1, bb = (bp & 1) * 4 + (hp >> 1);
    float sum0 = 0.f, sum1 = 0.f, sum2 = 0.f, sum3 = 0.f;
#pragma unroll
    for (int j = 0; j < 4; ++j) {
      const int hh = (hp & 1) * 4 + j;
      const float mean = meanw[32 + fi * 8 + hh];
      const float rstd = rstdw[32 + fi * 8 + hh];
      const float g = bng[hh], be = bnb[hh];
      const float4 x = *(const float4*)&conv[(size_t)(4 + fi) * 64 * 1024 +
                                             (size_t)bb * 8192 + hh * 1024 +
                                             4 * t];
      sum0 += bn_elu(x.x, mean, rstd, g, be);
      sum1 += bn_elu(x.y, mean, rstd, g, be);
      sum2 += bn_elu(x.z, mean, rstd, g, be);
      sum3 += bn_elu(x.w, mean, rstd, g, be);
    }
    v[0] = sum0 * 0.25f;
    v[1] = sum1 * 0.25f;
    v[2] = sum2 * 0.25f;
    v[3] = sum3 * 0.25f;
    sort1024(v, s, t);
    *(float4*)&Kt[(size_t)row * 1024 + 4 * t] =
        make_float4(v[0], v[1], v[2], v[3]);
  }
}

// ---------------- kernel 5: merge 4 sorted chunks -> top-1024 sorted --------
__global__ __launch_bounds__(256) void qmerge_kernel(
    const float* __restrict__ chunks, float* __restrict__ Qt) {
  __shared__ float s1[1024];
  __shared__ float s2[1024];
  const int t = threadIdx.x, row = blockIdx.x;
  const float* cb = chunks + (size_t)row * 4096;
  float a[4], b[4];
  {
    const float4 a0 = *(const float4*)&cb[4 * t];
    const float4 b0 = *(const float4*)&cb[2048 + 4 * t];
    float r1[4], r3[4];
#pragma unroll
    for (int e = 0; e < 4; ++e) {
      r1[e] = cb[1024 + 1023 - (4 * t + e)];
      r3[e] = cb[3072 + 1023 - (4 * t + e)];
    }
    a[0] = fmaxf(a0.x, r1[0]);
    a[1] = fmaxf(a0.y, r1[1]);
    a[2] = fmaxf(a0.z, r1[2]);
    a[3] = fmaxf(a0.w, r1[3]);
    b[0] = fmaxf(b0.x, r3[0]);
    b[1] = fmaxf(b0.y, r3[1]);
    b[2] = fmaxf(b0.z, r3[2]);
    b[3] = fmaxf(b0.w, r3[3]);
  }
  bmerge1024(a, s1, t);
  bmerge1024(b, s2, t);
  *(float4*)&s2[4 * t] = make_float4(b[0], b[1], b[2], b[3]);
  __syncthreads();
#pragma unroll
  for (int e = 0; e < 4; ++e) a[e] = fmaxf(a[e], s2[1023 - (4 * t + e)]);
  bmerge1024(a, s1, t);
  *(float4*)&Qt[(size_t)row * 1024 + 4 * t] =
      make_float4(a[0], a[1], a[2], a[3]);
}

// ---------------- kernel 6: softmax + attn write + MFMA PV (v3) -------------
// grid 1024 = 64 bh x 16 q-tiles of 64 rows; 256 threads (4 waves).
// Per 64-k chunk: V fp32->bf16 hi/lo into LDS [koct][d]; E-phase computes
// p = exp(s*k - m)*rz, writes fp32 attn to global, bf16 hi/lo to LDS
// [koct][q]; PV = 3x mfma_f32_16x16x32_bf16 per (q-tile, d-tile) per k-step.
// Fragment maps (gfx950): A row=l&15, k=8*(l>>4)+j; B col=l&15, same k;
// D col=l&15, row=4*(l>>4)+r.
__global__ __launch_bounds__(256, 4) void attn3_kernel(
    const float* __restrict__ V, const float* __restrict__ Qt,
    const float* __restrict__ Kt, const float* __restrict__ cw,
    float* __restrict__ ctx, float* __restrict__ attn) {
  __shared__ float Kts[1024];
  __shared__ float sq[64], mq[64], rz[64];
  __shared__ short Ehi[8 * 64 * 8];  // [koct][q][8k] bf16
  __shared__ short Elo[8 * 64 * 8];
  __shared__ short Vhi[8 * 64 * 8];  // [koct][d][8k] bf16
  __shared__ short Vlo[8 * 64 * 8];
  const int tid = threadIdx.x;
  const int b = blockIdx.x;
  // XCD swizzle: all 16 q-tiles of one bh on one XCD (1024 % 8 == 0).
  const int bh = ((b & 7) << 3) | ((b >> 3) & 7);
  const int qt = b >> 6;  // 0..15
  const int qbase = qt * 64;
  const float cval = cw[0];
  const float* Ktg = Kt + (size_t)bh * 1024;
  for (int t = tid; t < 1024; t += 256) Kts[t] = Ktg[t];
  const float kHi = Ktg[0], kLo = Ktg[1023];  // sorted descending
  if (tid < 64) {
    const float s = cval * Qt[(size_t)bh * 1024 + qbase + tid];
    sq[tid] = s;
    mq[tid] = fmaxf(s * kHi, s * kLo);
  }
  __syncthreads();
  {  // Z pass: 4 threads per q-row
    const int row = tid >> 2, qtr = tid & 3;
    const float s = sq[row], m = mq[row];
    float z = 0.f;
    const int k0 = qtr * 256;
    for (int k = 0; k < 256; ++k) z += __expf(fmaf(s, Kts[k0 + k], -m));
    z += __shfl_xor(z, 1, 64);
    z += __shfl_xor(z, 2, 64);
    if (qtr == 0) rz[row] = 1.f / z;
  }
  __syncthreads();

  const int wv = tid >> 6, l = tid & 63;
  const int l15 = l & 15, l4 = l >> 4;
  f32x4 acc[4];
#pragma unroll
  for (int dt = 0; dt < 4; ++dt) acc[dt] = (f32x4){0.f, 0.f, 0.f, 0.f};

  const float* Vb = V + (size_t)bh * 65536;
  float* arow = attn + ((size_t)bh << 20) + (size_t)qbase * 1024;
  const int dV = tid & 63, kqV = tid >> 6;  // V-convert roles

  for (int ch = 0; ch < 16; ++ch) {
    const int kc = ch * 64;
    // ---- V chunk fp32 -> bf16 hi/lo into LDS B-frag layout ----
#pragma unroll
    for (int g = 0; g < 2; ++g) {
      const int ko = kqV + g * 4;
      const float* vs = Vb + (size_t)(kc + ko * 8) * 64 + dV;
      bf16x8 vh, vl;
#pragma unroll
      for (int i = 0; i < 8; ++i) {
        const float f = vs[i * 64];
        const short h = f2bf(f);
        vh[i] = h;
        vl[i] = f2bf(f - bf2f(h));
      }
      *(bf16x8*)&Vhi[(ko * 64 + dV) * 8] = vh;
      *(bf16x8*)&Vlo[(ko * 64 + dV) * 8] = vl;
    }
    // ---- E phase: exp, normalize, global attn write, bf16 split ----
#pragma unroll
    for (int it = 0; it < 2; ++it) {
      const int q = wv * 16 + it * 8 + (l >> 3);
      const int ko = l & 7;
      const float s = sq[q], m = mq[q], r = rz[q];
      const float4 kv0 = *(const float4*)&Kts[kc + ko * 8];
      const float4 kv1 = *(const float4*)&Kts[kc + ko * 8 + 4];
      float e[8];
      e[0] = __expf(fmaf(s, kv0.x, -m)) * r;
      e[1] = __expf(fmaf(s, kv0.y, -m)) * r;
      e[2] = __expf(fmaf(s, kv0.z, -m)) * r;
      e[3] = __expf(fmaf(s, kv0.w, -m)) * r;
      e[4] = __expf(fmaf(s, kv1.x, -m)) * r;
      e[5] = __expf(fmaf(s, kv1.y, -m)) * r;
      e[6] = __expf(fmaf(s, kv1.z, -m)) * r;
      e[7] = __expf(fmaf(s, kv1.w, -m)) * r;
      float* ag = arow + (size_t)q * 1024 + kc + ko * 8;
      *(float4*)ag = make_float4(e[0], e[1], e[2], e[3]);
      *(float4*)(ag + 4) = make_float4(e[4], e[5], e[6], e[7]);
      bf16x8 eh, el;
#pragma unroll
      for (int i = 0; i < 8; ++i) {
        const short h = f2bf(e[i]);
        eh[i] = h;
        el[i] = f2bf(e[i] - bf2f(h));
      }
      *(bf16x8*)&Ehi[(ko * 64 + q) * 8] = eh;
      *(bf16x8*)&Elo[(ko * 64 + q) * 8] = el;
    }
    __syncthreads();
    // ---- PV: 2 k-steps x (1 q-tile x 4 d-tiles) x 3 split MFMAs ----
#pragma unroll
    for (int ks = 0; ks < 2; ++ks) {
      const int ko = ks * 4 + l4;
      const bf16x8 ah = *(const bf16x8*)&Ehi[(ko * 64 + wv * 16 + l15) * 8];
      const bf16x8 al = *(const bf16x8*)&Elo[(ko * 64 + wv * 16 + l15) * 8];
#pragma unroll
      for (int dt = 0; dt < 4; ++dt) {
        const bf16x8 bhv = *(const bf16x8*)&Vhi[(ko * 64 + dt * 16 + l15) * 8];
        const bf16x8 blv = *(const bf16x8*)&Vlo[(ko * 64 + dt * 16 + l15) * 8];
        acc[dt] = __builtin_amdgcn_mfma_f32_16x16x32_bf16(ah, bhv, acc[dt], 0, 0, 0);
        acc[dt] = __builtin_amdgcn_mfma_f32_16x16x32_bf16(ah, blv, acc[dt], 0, 0, 0);
        acc[dt] = __builtin_amdgcn_mfma_f32_16x16x32_bf16(al, bhv, acc[dt], 0, 0, 0);
      }
    }
    __syncthreads();
  }
  // ---- epilogue: ctx write (D: row = wv*16 + 4*l4 + r, col = dt*16 + l15)
  float* cb = ctx + ((size_t)bh * 1024 + qbase + wv * 16 + l4 * 4) * 64 + l15;
#pragma unroll
  for (int dt = 0; dt < 4; ++dt)
#pragma unroll
    for (int r = 0; r < 4; ++r) cb[(size_t)r * 64 + dt * 16] = acc[dt][r];
}

}  // namespace

extern "C" void kernel_launch(void* const* d_in, const int* in_sizes, int n_in,
                              void* d_out, int out_size, void* d_ws,
                              size_t ws_size, hipStream_t stream) {
  const float* Q = (const float*)d_in[0];
  const float* K = (const float*)d_in[1];
  const float* V = (const float*)d_in[2];
  const float* Wpq = (const float*)d_in[3];
  const float* Wbq = (const float*)d_in[4];
  const float* Wbk = (const float*)d_in[5];
  const float* bng = (const float*)d_in[6];
  const float* bnb = (const float*)d_in[7];
  // d_in[8] = attn_mask (all ones, unused)
  const float* cqw[4] = {(const float*)d_in[9], (const float*)d_in[13],
                         (const float*)d_in[17], (const float*)d_in[21]};
  const float* cqb[4] = {(const float*)d_in[10], (const float*)d_in[14],
                         (const float*)d_in[18], (const float*)d_in[22]};
  const float* ckw[4] = {(const float*)d_in[11], (const float*)d_in[15],
                         (const float*)d_in[19], (const float*)d_in[23]};
  const float* ckb[4] = {(const float*)d_in[12], (const float*)d_in[16],
                         (const float*)d_in[20], (const float*)d_in[24]};

  float* ws = (float*)d_ws;
  float* proj = ws + PROJ_OFF;
  float* conv = ws + CONV_OFF;
  float* meanw = ws + MEAN_OFF;
  float* rstdw = ws + RSTD_OFF;
  float* cw = ws + C_OFF;
  float* Qtp = ws + QT_OFF;
  float* Ktp = ws + KT_OFF;
  float* ctx = (float*)d_out;
  float* attn = ctx + (size_t)8 * 8 * 1024 * 64;
  // Q chunk scratch: reuse the attn output region (fully overwritten by
  // attn3_kernel afterwards, so timed-replay re-validation stays correct).
  float* chunks = attn;  // [64][4][1024] floats

  proj_kernel<<<512, 256, 0, stream>>>(Q, K, Wpq, proj);
  conv_kernel<<<64, 256, 0, stream>>>(
      proj, cqw[0], cqb[0], cqw[1], cqb[1], cqw[2], cqb[2], cqw[3], cqb[3],
      ckw[0], ckb[0], ckw[1], ckb[1], ckw[2], ckb[2], ckw[3], ckb[3], conv);
  stats_kernel<<<64, 256, 0, stream>>>(conv, Wbq, Wbk, meanw, rstdw, cw);
  chunksort_kernel<<<320, 256, 0, stream>>>(conv, meanw, rstdw, bng, bnb,
                                            chunks, Ktp);
  qmerge_kernel<<<64, 256, 0, stream>>>(chunks, Qtp);
  attn3_kernel<<<1024, 256, 0, stream>>>(V, Qtp, Ktp, cw, ctx, attn);
}

// Round 5
// 121.911 us; speedup vs baseline: 5.4825x; 1.6790x over previous
//
#include <hip/hip_runtime.h>
#include <math.h>

// ---------------- workspace layout (float offsets) ----------------
// proj  [2][8][8][1024]            @ 0        (131072)
// conv  [2][4][8][8][1024]         @ 131072   (524288)
// mean  [2][4][8]                  @ 655360   (64)
// rstd  [2][4][8]                  @ 655424   (64)
// c     [1]                        @ 655488
// Qt    [64][1024]                 @ 655616   (65536)
// Kt    [64][1024]                 @ 721152   (65536)
// Q chunk scratch lives in d_out's attn region (overwritten by attn4 later).
namespace {
constexpr int PROJ_OFF = 0;
constexpr int CONV_OFF = 131072;
constexpr int MEAN_OFF = 655360;
constexpr int RSTD_OFF = 655424;
constexpr int C_OFF    = 655488;
constexpr int QT_OFF   = 655616;
constexpr int KT_OFF   = 721152;

typedef short bf16x8 __attribute__((ext_vector_type(8)));
typedef float f32x4 __attribute__((ext_vector_type(4)));

__device__ inline short f2bf(float f) {
  union { float f; unsigned u; } c;
  c.f = f;
  const unsigned r = (c.u + 0x7fffu + ((c.u >> 16) & 1u)) >> 16;
  return (short)r;
}
__device__ inline float bf2f(short b) {
  union { unsigned u; float f; } c;
  c.u = ((unsigned)(unsigned short)b) << 16;
  return c.f;
}

// ---------------- kernel 1: projection q/k = X . W_pq (1 row/thread) -------
__global__ __launch_bounds__(256) void proj_kernel(
    const float* __restrict__ Q, const float* __restrict__ K,
    const float* __restrict__ Wpq, float* __restrict__ proj) {
  __shared__ float wsh[64];
  const int tid = threadIdx.x;
  if (tid < 64) wsh[tid] = Wpq[tid];
  __syncthreads();
  const int row = blockIdx.x * 256 + tid;  // 0..131071
  const float* src = (row < 65536) ? (Q + (size_t)row * 64)
                                   : (K + (size_t)(row - 65536) * 64);
  float acc = 0.f;
#pragma unroll
  for (int j = 0; j < 16; ++j) {
    const float4 v = *(const float4*)(src + j * 4);
    acc = fmaf(v.x, wsh[j * 4 + 0], acc);
    acc = fmaf(v.y, wsh[j * 4 + 1], acc);
    acc = fmaf(v.z, wsh[j * 4 + 2], acc);
    acc = fmaf(v.w, wsh[j * 4 + 3], acc);
  }
  proj[row] = acc;
}

// ---------------- kernel 2: conv1d (4 filters x 2 paths, L-split x4) -------
template <int F>
__device__ void conv_body(const float* __restrict__ xs,
                          const float* __restrict__ wsm,
                          const float* __restrict__ bsm,
                          float* __restrict__ outp, int tid, int lq) {
  constexpr int pad = (F - 1) / 2;
  for (int e = tid; e < 2048; e += 256) {
    const int o = e >> 8, l = e & 255;
    float acc = bsm[o];
#pragma unroll
    for (int c = 0; c < 8; ++c) {
      const float* xrow = &xs[c * 264 + l + 4 - pad];
      const float* wrow = &wsm[(o * 8 + c) * F];
#pragma unroll
      for (int f = 0; f < F; ++f) acc = fmaf(xrow[f], wrow[f], acc);
    }
    outp[o * 1024 + lq * 256 + l] = acc;
  }
}

__global__ __launch_bounds__(256) void conv_kernel(
    const float* __restrict__ proj,
    const float* __restrict__ wq0, const float* __restrict__ bq0,
    const float* __restrict__ wq1, const float* __restrict__ bq1,
    const float* __restrict__ wq2, const float* __restrict__ bq2,
    const float* __restrict__ wq3, const float* __restrict__ bq3,
    const float* __restrict__ wk0, const float* __restrict__ bk0,
    const float* __restrict__ wk1, const float* __restrict__ bk1,
    const float* __restrict__ wk2, const float* __restrict__ bk2,
    const float* __restrict__ wk3, const float* __restrict__ bk3,
    float* __restrict__ conv) {
  __shared__ float xs[8 * 264];  // halo of 4 each side
  __shared__ float wsm[8 * 8 * 9];
  __shared__ float bsm[8];
  const int tid = threadIdx.x;
  const int blk = blockIdx.x;  // 256 blocks: (path, filt, batch, lq)
  const int path = blk >> 7, fi = (blk >> 5) & 3, bb = (blk >> 2) & 7;
  const int lq = blk & 3;
  const int F = (0x9731 >> (fi * 4)) & 0xF;  // 1,3,7,9
  const float* wp;
  const float* bp;
  if (path == 0) {
    wp = fi == 0 ? wq0 : fi == 1 ? wq1 : fi == 2 ? wq2 : wq3;
    bp = fi == 0 ? bq0 : fi == 1 ? bq1 : fi == 2 ? bq2 : bq3;
  } else {
    wp = fi == 0 ? wk0 : fi == 1 ? wk1 : fi == 2 ? wk2 : wk3;
    bp = fi == 0 ? bk0 : fi == 1 ? bk1 : fi == 2 ? bk2 : bk3;
  }
  const float* pb = proj + path * 65536 + bb * 8192;
  for (int e = tid; e < 8 * 264; e += 256) {
    const int c = e / 264, pos = e - c * 264;
    const int gl = lq * 256 + pos - 4;
    xs[e] = (gl >= 0 && gl < 1024) ? pb[c * 1024 + gl] : 0.f;
  }
  for (int e = tid; e < 64 * F; e += 256) wsm[e] = wp[e];
  if (tid < 8) bsm[tid] = bp[tid];
  __syncthreads();
  float* outp = conv + ((size_t)(path * 4 + fi) * 8 + bb) * 8192;
  if (fi == 0)
    conv_body<1>(xs, wsm, bsm, outp, tid, lq);
  else if (fi == 1)
    conv_body<3>(xs, wsm, bsm, outp, tid, lq);
  else if (fi == 2)
    conv_body<7>(xs, wsm, bsm, outp, tid, lq);
  else
    conv_body<9>(xs, wsm, bsm, outp, tid, lq);
}

// ---------------- kernel 3: BN batch stats + scalar c ----------------
__global__ __launch_bounds__(256) void stats_kernel(
    const float* __restrict__ conv,
    const float* __restrict__ Wbq, const float* __restrict__ Wbk,
    float* __restrict__ meanw, float* __restrict__ rstdw,
    float* __restrict__ cw) {
  __shared__ float r1[256], r2[256];
  const int tid = threadIdx.x, blk = blockIdx.x;  // blk = path*32+fi*8+o
  const int o = blk & 7;
  const size_t base = (size_t)(blk >> 3) * 8 * 8192 + (size_t)o * 1024;
  float s = 0.f, ss = 0.f;
  for (int e = tid; e < 8192; e += 256) {
    const int bb = e >> 10, l = e & 1023;
    const float v = conv[base + (size_t)bb * 8192 + l];
    s += v;
    ss += v * v;
  }
  r1[tid] = s;
  r2[tid] = ss;
  __syncthreads();
  for (int st = 128; st > 0; st >>= 1) {
    if (tid < st) {
      r1[tid] += r1[tid + st];
      r2[tid] += r2[tid + st];
    }
    __syncthreads();
  }
  if (tid == 0) {
    const float mean = r1[0] * (1.f / 8192.f);
    const float var = r2[0] * (1.f / 8192.f) - mean * mean;
    meanw[blk] = mean;
    rstdw[blk] = rsqrtf(fmaxf(var, 0.f) + 1e-5f);
  }
  if (blk == 0 && tid == 0) {
    float d = 0.f;
    for (int i = 0; i < 64; ++i) d += Wbq[i] * Wbk[i];
    cw[0] = d * 0.125f;  // / sqrt(64)
  }
}

__device__ inline float bn_elu(float v, float mean, float rstd, float g,
                               float be) {
  const float x = (v - mean) * rstd * g + be;
  return x > 0.f ? x : expm1f(x);
}

// ============ register/shuffle bitonic sort machinery ============
__device__ inline void cswap(float& a, float& b, bool up) {
  const float mx = fmaxf(a, b), mn = fminf(a, b);
  a = up ? mx : mn;
  b = up ? mn : mx;
}

__device__ inline void shfl_pass(float v[4], int t, int m, bool up) {
  const bool keepmax = (up == ((t & m) == 0));
#pragma unroll
  for (int e = 0; e < 4; ++e) {
    const float p = __shfl_xor(v[e], m, 64);
    v[e] = keepmax ? fmaxf(v[e], p) : fminf(v[e], p);
  }
}

__device__ inline void lds_pass(float v[4], float* s, int t, int jq, bool up) {
  *(float4*)&s[4 * t] = make_float4(v[0], v[1], v[2], v[3]);
  __syncthreads();
  const int pt = t ^ jq;
  const bool keepmax = (up == ((t & jq) == 0));
  const float4 p = *(const float4*)&s[4 * pt];
  v[0] = keepmax ? fmaxf(v[0], p.x) : fminf(v[0], p.x);
  v[1] = keepmax ? fmaxf(v[1], p.y) : fminf(v[1], p.y);
  v[2] = keepmax ? fmaxf(v[2], p.z) : fminf(v[2], p.z);
  v[3] = keepmax ? fmaxf(v[3], p.w) : fminf(v[3], p.w);
  __syncthreads();
}

__device__ inline void reg_tail(float v[4], int t, bool up) {
#pragma unroll
  for (int m = 32; m >= 1; m >>= 1) shfl_pass(v, t, m, up);
  cswap(v[0], v[2], up);
  cswap(v[1], v[3], up);
  cswap(v[0], v[1], up);
  cswap(v[2], v[3], up);
}

__device__ inline void sort1024(float v[4], float* s, int t) {
  cswap(v[0], v[1], true);
  cswap(v[2], v[3], false);
#pragma unroll
  for (int k = 4; k <= 256; k <<= 1) {
    const bool up = ((t & (k >> 2)) == 0);
    for (int m = k >> 3; m >= 1; m >>= 1) shfl_pass(v, t, m, up);
    cswap(v[0], v[2], up);
    cswap(v[1], v[3], up);
    cswap(v[0], v[1], up);
    cswap(v[2], v[3], up);
  }
  {
    const bool up = ((t & 128) == 0);
    lds_pass(v, s, t, 64, up);
    reg_tail(v, t, up);
  }
  lds_pass(v, s, t, 128, true);
  lds_pass(v, s, t, 64, true);
  reg_tail(v, t, true);
}

__device__ inline void bmerge1024(float v[4], float* s, int t) {
  lds_pass(v, s, t, 128, true);
  lds_pass(v, s, t, 64, true);
  reg_tail(v, t, true);
}

// ---------------- kernel 4: per-chunk BN/ELU + sort ----------------
__global__ __launch_bounds__(256) void chunksort_kernel(
    const float* __restrict__ conv, const float* __restrict__ meanw,
    const float* __restrict__ rstdw, const float* __restrict__ bng,
    const float* __restrict__ bnb, float* __restrict__ chunks,
    float* __restrict__ Kt) {
  __shared__ float s[1024];
  const int t = threadIdx.x, blk = blockIdx.x;
  float v[4];
  if (blk < 256) {
    const int row = blk >> 2, jc = blk & 3;
    const int bp = row >> 3, hp = row & 7;
    const int fi = bp >> 1, bb = (bp & 1) * 4 + (hp >> 1);
    const int hh = (hp & 1) * 4 + jc;
    const float mean = meanw[fi * 8 + hh], rstd = rstdw[fi * 8 + hh];
    const float g = bng[hh], be = bnb[hh];
    const float4 x = *(const float4*)&conv[(size_t)(fi * 8 + bb) * 8192 +
                                           hh * 1024 + 4 * t];
    v[0] = bn_elu(x.x, mean, rstd, g, be);
    v[1] = bn_elu(x.y, mean, rstd, g, be);
    v[2] = bn_elu(x.z, mean, rstd, g, be);
    v[3] = bn_elu(x.w, mean, rstd, g, be);
    sort1024(v, s, t);
    *(float4*)&chunks[(size_t)blk * 1024 + 4 * t] =
        make_float4(v[0], v[1], v[2], v[3]);
  } else {
    const int row = blk - 256;
    const int bp = row >> 3, hp = row & 7;
    const int fi = bp >> 1, bb = (bp & 1) * 4 + (hp >> 1);
    float sum0 = 0.f, sum1 = 0.f, sum2 = 0.f, sum3 = 0.f;
#pragma unroll
    for (int j = 0; j < 4; ++j) {
      const int hh = (hp & 1) * 4 + j;
      const float mean = meanw[32 + fi * 8 + hh];
      const float rstd = rstdw[32 + fi * 8 + hh];
      const float g = bng[hh], be = bnb[hh];
      const float4 x = *(const float4*)&conv[(size_t)(4 + fi) * 64 * 1024 +
                                             (size_t)bb * 8192 + hh * 1024 +
                                             4 * t];
      sum0 += bn_elu(x.x, mean, rstd, g, be);
      sum1 += bn_elu(x.y, mean, rstd, g, be);
      sum2 += bn_elu(x.z, mean, rstd, g, be);
      sum3 += bn_elu(x.w, mean, rstd, g, be);
    }
    v[0] = sum0 * 0.25f;
    v[1] = sum1 * 0.25f;
    v[2] = sum2 * 0.25f;
    v[3] = sum3 * 0.25f;
    sort1024(v, s, t);
    *(float4*)&Kt[(size_t)row * 1024 + 4 * t] =
        make_float4(v[0], v[1], v[2], v[3]);
  }
}

// ---------------- kernel 5: merge 4 sorted chunks -> top-1024 sorted --------
__global__ __launch_bounds__(256) void qmerge_kernel(
    const float* __restrict__ chunks, float* __restrict__ Qt) {
  __shared__ float s1[1024];
  __shared__ float s2[1024];
  const int t = threadIdx.x, row = blockIdx.x;
  const float* cb = chunks + (size_t)row * 4096;
  float a[4], b[4];
  {
    const float4 a0 = *(const float4*)&cb[4 * t];
    const float4 b0 = *(const float4*)&cb[2048 + 4 * t];
    float r1[4], r3[4];
#pragma unroll
    for (int e = 0; e < 4; ++e) {
      r1[e] = cb[1024 + 1023 - (4 * t + e)];
      r3[e] = cb[3072 + 1023 - (4 * t + e)];
    }
    a[0] = fmaxf(a0.x, r1[0]);
    a[1] = fmaxf(a0.y, r1[1]);
    a[2] = fmaxf(a0.z, r1[2]);
    a[3] = fmaxf(a0.w, r1[3]);
    b[0] = fmaxf(b0.x, r3[0]);
    b[1] = fmaxf(b0.y, r3[1]);
    b[2] = fmaxf(b0.z, r3[2]);
    b[3] = fmaxf(b0.w, r3[3]);
  }
  bmerge1024(a, s1, t);
  bmerge1024(b, s2, t);
  *(float4*)&s2[4 * t] = make_float4(b[0], b[1], b[2], b[3]);
  __syncthreads();
#pragma unroll
  for (int e = 0; e < 4; ++e) a[e] = fmaxf(a[e], s2[1023 - (4 * t + e)]);
  bmerge1024(a, s1, t);
  *(float4*)&Qt[(size_t)row * 1024 + 4 * t] =
      make_float4(a[0], a[1], a[2], a[3]);
}

// ---------------- kernel 6: softmax + attn write + MFMA PV (v4) -------------
// grid 1024 = 64 bh x 16 q-tiles of 64 rows; 256 threads (4 waves).
// A-fragments computed directly in registers (no E LDS): lane l of wave wv
// owns q = wv*16 + (l&15), k = kc + ks*32 + 8*(l>>4) + j  (the exact
// mfma_f32_16x16x32_bf16 A map). V staged in double-buffered LDS as bf16
// hi/lo B-frags [ko][d][8k]; one barrier per 64-k chunk.
__global__ __launch_bounds__(256, 4) void attn4_kernel(
    const float* __restrict__ V, const float* __restrict__ Qt,
    const float* __restrict__ Kt, const float* __restrict__ cw,
    float* __restrict__ ctx, float* __restrict__ attn) {
  __shared__ float Kts[1024];
  __shared__ float sq[64], mq[64], rz[64];
  __shared__ short Vhi[2][8 * 64 * 8];  // [buf][ko][d][8k] bf16
  __shared__ short Vlo[2][8 * 64 * 8];
  const int tid = threadIdx.x;
  const int b = blockIdx.x;
  // XCD swizzle: all 16 q-tiles of one bh on one XCD (1024 % 8 == 0).
  const int bh = ((b & 7) << 3) | ((b >> 3) & 7);
  const int qt = b >> 6;  // 0..15
  const int qbase = qt * 64;
  const float cval = cw[0];
  const float* Ktg = Kt + (size_t)bh * 1024;
  for (int t = tid; t < 1024; t += 256) Kts[t] = Ktg[t];
  const float kHi = Ktg[0], kLo = Ktg[1023];  // sorted descending
  if (tid < 64) {
    const float s = cval * Qt[(size_t)bh * 1024 + qbase + tid];
    sq[tid] = s;
    mq[tid] = fmaxf(s * kHi, s * kLo);
  }
  __syncthreads();
  {  // Z pass: 4 threads per q-row
    const int row = tid >> 2, qtr = tid & 3;
    const float s = sq[row], m = mq[row];
    float z = 0.f;
    const int k0 = qtr * 256;
    for (int k = 0; k < 256; ++k) z += __expf(fmaf(s, Kts[k0 + k], -m));
    z += __shfl_xor(z, 1, 64);
    z += __shfl_xor(z, 2, 64);
    if (qtr == 0) rz[row] = 1.f / z;
  }
  __syncthreads();

  const int wv = tid >> 6, l = tid & 63;
  const int l15 = l & 15, l4 = l >> 4;
  const int q = wv * 16 + l15;  // this lane's A-frag row
  const float s = sq[q], m = mq[q], r = rz[q];
  f32x4 acc[4];
#pragma unroll
  for (int dt = 0; dt < 4; ++dt) acc[dt] = (f32x4){0.f, 0.f, 0.f, 0.f};

  const float* Vb = V + (size_t)bh * 65536;
  float* arow = attn + ((size_t)bh << 20) + (size_t)qbase * 1024;
  const int dV = tid & 63, kqV = tid >> 6;  // V-convert roles

  for (int ch = 0; ch < 16; ++ch) {
    const int kc = ch * 64;
    const int buf = ch & 1;
    // ---- (a) issue V global loads early (latency hides under E-phase) ----
    float vreg[2][8];
#pragma unroll
    for (int g = 0; g < 2; ++g) {
      const int ko = kqV + g * 4;
      const float* vs = Vb + (size_t)(kc + ko * 8) * 64 + dV;
#pragma unroll
      for (int i = 0; i < 8; ++i) vreg[g][i] = vs[i * 64];
    }
    // ---- (b) E-phase in registers: exp -> attn write -> bf16 hi/lo ----
    bf16x8 ahi[2], alo[2];
#pragma unroll
    for (int ks = 0; ks < 2; ++ks) {
      const int kb = kc + ks * 32 + l4 * 8;
      const float4 kv0 = *(const float4*)&Kts[kb];
      const float4 kv1 = *(const float4*)&Kts[kb + 4];
      float e[8];
      e[0] = __expf(fmaf(s, kv0.x, -m)) * r;
      e[1] = __expf(fmaf(s, kv0.y, -m)) * r;
      e[2] = __expf(fmaf(s, kv0.z, -m)) * r;
      e[3] = __expf(fmaf(s, kv0.w, -m)) * r;
      e[4] = __expf(fmaf(s, kv1.x, -m)) * r;
      e[5] = __expf(fmaf(s, kv1.y, -m)) * r;
      e[6] = __expf(fmaf(s, kv1.z, -m)) * r;
      e[7] = __expf(fmaf(s, kv1.w, -m)) * r;
      float* ag = arow + (size_t)q * 1024 + kb;
      *(float4*)ag = make_float4(e[0], e[1], e[2], e[3]);
      *(float4*)(ag + 4) = make_float4(e[4], e[5], e[6], e[7]);
#pragma unroll
      for (int i = 0; i < 8; ++i) {
        const short h = f2bf(e[i]);
        ahi[ks][i] = h;
        alo[ks][i] = f2bf(e[i] - bf2f(h));
      }
    }
    // ---- (c) convert V and commit to LDS B-frag layout ----
#pragma unroll
    for (int g = 0; g < 2; ++g) {
      const int ko = kqV + g * 4;
      bf16x8 vh, vl;
#pragma unroll
      for (int i = 0; i < 8; ++i) {
        const float f = vreg[g][i];
        const short h = f2bf(f);
        vh[i] = h;
        vl[i] = f2bf(f - bf2f(h));
      }
      *(bf16x8*)&Vhi[buf][(ko * 64 + dV) * 8] = vh;
      *(bf16x8*)&Vlo[buf][(ko * 64 + dV) * 8] = vl;
    }
    __syncthreads();
    // ---- (d) PV: A from regs, B from LDS; 3 split MFMAs per (ks, dt) ----
#pragma unroll
    for (int ks = 0; ks < 2; ++ks) {
      const int ko = ks * 4 + l4;
#pragma unroll
      for (int dt = 0; dt < 4; ++dt) {
        const bf16x8 bhv =
            *(const bf16x8*)&Vhi[buf][(ko * 64 + dt * 16 + l15) * 8];
        const bf16x8 blv =
            *(const bf16x8*)&Vlo[buf][(ko * 64 + dt * 16 + l15) * 8];
        acc[dt] =
            __builtin_amdgcn_mfma_f32_16x16x32_bf16(ahi[ks], bhv, acc[dt], 0, 0, 0);
        acc[dt] =
            __builtin_amdgcn_mfma_f32_16x16x32_bf16(ahi[ks], blv, acc[dt], 0, 0, 0);
        acc[dt] =
            __builtin_amdgcn_mfma_f32_16x16x32_bf16(alo[ks], bhv, acc[dt], 0, 0, 0);
      }
    }
  }
  // ---- epilogue: ctx write (D: row = wv*16 + 4*l4 + r, col = dt*16 + l15)
  float* cb = ctx + ((size_t)bh * 1024 + qbase + wv * 16 + l4 * 4) * 64 + l15;
#pragma unroll
  for (int dt = 0; dt < 4; ++dt)
#pragma unroll
    for (int rr = 0; rr < 4; ++rr) cb[(size_t)rr * 64 + dt * 16] = acc[dt][rr];
}

}  // namespace

extern "C" void kernel_launch(void* const* d_in, const int* in_sizes, int n_in,
                              void* d_out, int out_size, void* d_ws,
                              size_t ws_size, hipStream_t stream) {
  const float* Q = (const float*)d_in[0];
  const float* K = (const float*)d_in[1];
  const float* V = (const float*)d_in[2];
  const float* Wpq = (const float*)d_in[3];
  const float* Wbq = (const float*)d_in[4];
  const float* Wbk = (const float*)d_in[5];
  const float* bng = (const float*)d_in[6];
  const float* bnb = (const float*)d_in[7];
  // d_in[8] = attn_mask (all ones, unused)
  const float* cqw[4] = {(const float*)d_in[9], (const float*)d_in[13],
                         (const float*)d_in[17], (const float*)d_in[21]};
  const float* cqb[4] = {(const float*)d_in[10], (const float*)d_in[14],
                         (const float*)d_in[18], (const float*)d_in[22]};
  const float* ckw[4] = {(const float*)d_in[11], (const float*)d_in[15],
                         (const float*)d_in[19], (const float*)d_in[23]};
  const float* ckb[4] = {(const float*)d_in[12], (const float*)d_in[16],
                         (const float*)d_in[20], (const float*)d_in[24]};

  float* ws = (float*)d_ws;
  float* proj = ws + PROJ_OFF;
  float* conv = ws + CONV_OFF;
  float* meanw = ws + MEAN_OFF;
  float* rstdw = ws + RSTD_OFF;
  float* cw = ws + C_OFF;
  float* Qtp = ws + QT_OFF;
  float* Ktp = ws + KT_OFF;
  float* ctx = (float*)d_out;
  float* attn = ctx + (size_t)8 * 8 * 1024 * 64;
  // Q chunk scratch: reuse the attn output region (fully overwritten by
  // attn4_kernel afterwards, so timed-replay re-validation stays correct).
  float* chunks = attn;  // [64][4][1024] floats

  proj_kernel<<<512, 256, 0, stream>>>(Q, K, Wpq, proj);
  conv_kernel<<<256, 256, 0, stream>>>(
      proj, cqw[0], cqb[0], cqw[1], cqb[1], cqw[2], cqb[2], cqw[3], cqb[3],
      ckw[0], ckb[0], ckw[1], ckb[1], ckw[2], ckb[2], ckw[3], ckb[3], conv);
  stats_kernel<<<64, 256, 0, stream>>>(conv, Wbq, Wbk, meanw, rstdw, cw);
  chunksort_kernel<<<320, 256, 0, stream>>>(conv, meanw, rstdw, bng, bnb,
                                            chunks, Ktp);
  qmerge_kernel<<<64, 256, 0, stream>>>(chunks, Qtp);
  attn4_kernel<<<1024, 256, 0, stream>>>(V, Qtp, Ktp, cw, ctx, attn);
}

// Round 6
// 119.813 us; speedup vs baseline: 5.5785x; 1.0175x over previous
//
#include <hip/hip_runtime.h>
#include <hip/hip_bf16.h>
#include <math.h>

// ---------------- workspace layout (float offsets) ----------------
// proj  [2][8][8][1024]            @ 0        (131072)
// conv  [2][4][8][8][1024]         @ 131072   (524288)
// psum  [64][32]                   @ 655360   (2048)
// psumsq[64][32]                   @ 657408   (2048)
// Qt    [64][1024]                 @ 659456   (65536)
// Kt    [64][1024]                 @ 724992   (65536)
namespace {
constexpr int PROJ_OFF = 0;
constexpr int CONV_OFF = 131072;
constexpr int PS_OFF   = 655360;
constexpr int PSS_OFF  = 657408;
constexpr int QT_OFF   = 659456;
constexpr int KT_OFF   = 724992;

typedef short bf16x8 __attribute__((ext_vector_type(8)));
typedef float f32x4 __attribute__((ext_vector_type(4)));

union BF8 {
  bf16x8 v;
  short s[8];
};

// ---------------- kernel 1: projection q/k = X . W_pq (1 row/thread) -------
__global__ __launch_bounds__(256) void proj_kernel(
    const float* __restrict__ Q, const float* __restrict__ K,
    const float* __restrict__ Wpq, float* __restrict__ proj) {
  __shared__ float wsh[64];
  const int tid = threadIdx.x;
  if (tid < 64) wsh[tid] = Wpq[tid];
  __syncthreads();
  const int row = blockIdx.x * 256 + tid;  // 0..131071
  const float* src = (row < 65536) ? (Q + (size_t)row * 64)
                                   : (K + (size_t)(row - 65536) * 64);
  float acc = 0.f;
#pragma unroll
  for (int j = 0; j < 16; ++j) {
    const float4 v = *(const float4*)(src + j * 4);
    acc = fmaf(v.x, wsh[j * 4 + 0], acc);
    acc = fmaf(v.y, wsh[j * 4 + 1], acc);
    acc = fmaf(v.z, wsh[j * 4 + 2], acc);
    acc = fmaf(v.w, wsh[j * 4 + 3], acc);
  }
  proj[row] = acc;
}

// ---------------- kernel 2: conv1d + per-block BN partial sums --------------
template <int F>
__device__ void conv_body(const float* __restrict__ xs,
                          const float* __restrict__ wsm,
                          const float* __restrict__ bsm,
                          float* __restrict__ outp, int tid, int lq,
                          float accs[8]) {
  constexpr int pad = (F - 1) / 2;
#pragma unroll
  for (int j = 0; j < 8; ++j) {
    float acc = bsm[j];
#pragma unroll
    for (int c = 0; c < 8; ++c) {
      const float* xrow = &xs[c * 264 + tid + 4 - pad];
      const float* wrow = &wsm[(j * 8 + c) * F];
#pragma unroll
      for (int f = 0; f < F; ++f) acc = fmaf(xrow[f], wrow[f], acc);
    }
    outp[j * 1024 + lq * 256 + tid] = acc;
    accs[j] = acc;
  }
}

__global__ __launch_bounds__(256) void conv_kernel(
    const float* __restrict__ proj,
    const float* __restrict__ wq0, const float* __restrict__ bq0,
    const float* __restrict__ wq1, const float* __restrict__ bq1,
    const float* __restrict__ wq2, const float* __restrict__ bq2,
    const float* __restrict__ wq3, const float* __restrict__ bq3,
    const float* __restrict__ wk0, const float* __restrict__ bk0,
    const float* __restrict__ wk1, const float* __restrict__ bk1,
    const float* __restrict__ wk2, const float* __restrict__ bk2,
    const float* __restrict__ wk3, const float* __restrict__ bk3,
    float* __restrict__ conv, float* __restrict__ psum,
    float* __restrict__ psumsq) {
  __shared__ float xs[8 * 264];  // halo of 4 each side
  __shared__ float wsm[8 * 8 * 9];
  __shared__ float bsm[8];
  __shared__ float redS[8][4], redSS[8][4];
  const int tid = threadIdx.x;
  const int blk = blockIdx.x;  // 256 blocks: (path, filt, batch, lq)
  const int path = blk >> 7, fi = (blk >> 5) & 3, bb = (blk >> 2) & 7;
  const int lq = blk & 3;
  const int F = (0x9731 >> (fi * 4)) & 0xF;  // 1,3,7,9
  const float* wp;
  const float* bp;
  if (path == 0) {
    wp = fi == 0 ? wq0 : fi == 1 ? wq1 : fi == 2 ? wq2 : wq3;
    bp = fi == 0 ? bq0 : fi == 1 ? bq1 : fi == 2 ? bq2 : bq3;
  } else {
    wp = fi == 0 ? wk0 : fi == 1 ? wk1 : fi == 2 ? wk2 : wk3;
    bp = fi == 0 ? bk0 : fi == 1 ? bk1 : fi == 2 ? bk2 : bk3;
  }
  const float* pb = proj + path * 65536 + bb * 8192;
  for (int e = tid; e < 8 * 264; e += 256) {
    const int c = e / 264, pos = e - c * 264;
    const int gl = lq * 256 + pos - 4;
    xs[e] = (gl >= 0 && gl < 1024) ? pb[c * 1024 + gl] : 0.f;
  }
  for (int e = tid; e < 64 * F; e += 256) wsm[e] = wp[e];
  if (tid < 8) bsm[tid] = bp[tid];
  __syncthreads();
  float* outp = conv + ((size_t)(path * 4 + fi) * 8 + bb) * 8192;
  float accs[8];
  if (fi == 0)
    conv_body<1>(xs, wsm, bsm, outp, tid, lq, accs);
  else if (fi == 1)
    conv_body<3>(xs, wsm, bsm, outp, tid, lq, accs);
  else if (fi == 2)
    conv_body<7>(xs, wsm, bsm, outp, tid, lq, accs);
  else
    conv_body<9>(xs, wsm, bsm, outp, tid, lq, accs);
  // block reduction of per-channel sum / sumsq (deterministic, no atomics)
  const int lane = tid & 63, wv = tid >> 6;
#pragma unroll
  for (int j = 0; j < 8; ++j) {
    float sv = accs[j], qv = accs[j] * accs[j];
#pragma unroll
    for (int mm = 32; mm >= 1; mm >>= 1) {
      sv += __shfl_xor(sv, mm, 64);
      qv += __shfl_xor(qv, mm, 64);
    }
    if (lane == 0) {
      redS[j][wv] = sv;
      redSS[j][wv] = qv;
    }
  }
  __syncthreads();
  if (tid < 16) {
    const int j = tid & 7;
    const bool wantss = tid >= 8;
    const float* rr = wantss ? &redSS[j][0] : &redS[j][0];
    const float tot = rr[0] + rr[1] + rr[2] + rr[3];
    float* dst = wantss ? psumsq : psum;
    dst[((path * 4 + fi) * 8 + j) * 32 + bb * 4 + lq] = tot;
  }
}

__device__ inline float bn_elu(float v, float mean, float rstd, float g,
                               float be) {
  const float x = (v - mean) * rstd * g + be;
  return x > 0.f ? x : expm1f(x);
}

// ============ register/shuffle bitonic sort machinery ============
__device__ inline void cswap(float& a, float& b, bool up) {
  const float mx = fmaxf(a, b), mn = fminf(a, b);
  a = up ? mx : mn;
  b = up ? mn : mx;
}

__device__ inline void shfl_pass(float v[4], int t, int m, bool up) {
  const bool keepmax = (up == ((t & m) == 0));
#pragma unroll
  for (int e = 0; e < 4; ++e) {
    const float p = __shfl_xor(v[e], m, 64);
    v[e] = keepmax ? fmaxf(v[e], p) : fminf(v[e], p);
  }
}

__device__ inline void lds_pass(float v[4], float* s, int t, int jq, bool up) {
  *(float4*)&s[4 * t] = make_float4(v[0], v[1], v[2], v[3]);
  __syncthreads();
  const int pt = t ^ jq;
  const bool keepmax = (up == ((t & jq) == 0));
  const float4 p = *(const float4*)&s[4 * pt];
  v[0] = keepmax ? fmaxf(v[0], p.x) : fminf(v[0], p.x);
  v[1] = keepmax ? fmaxf(v[1], p.y) : fminf(v[1], p.y);
  v[2] = keepmax ? fmaxf(v[2], p.z) : fminf(v[2], p.z);
  v[3] = keepmax ? fmaxf(v[3], p.w) : fminf(v[3], p.w);
  __syncthreads();
}

__device__ inline void reg_tail(float v[4], int t, bool up) {
#pragma unroll
  for (int m = 32; m >= 1; m >>= 1) shfl_pass(v, t, m, up);
  cswap(v[0], v[2], up);
  cswap(v[1], v[3], up);
  cswap(v[0], v[1], up);
  cswap(v[2], v[3], up);
}

__device__ inline void sort1024(float v[4], float* s, int t) {
  cswap(v[0], v[1], true);
  cswap(v[2], v[3], false);
#pragma unroll
  for (int k = 4; k <= 256; k <<= 1) {
    const bool up = ((t & (k >> 2)) == 0);
    for (int m = k >> 3; m >= 1; m >>= 1) shfl_pass(v, t, m, up);
    cswap(v[0], v[2], up);
    cswap(v[1], v[3], up);
    cswap(v[0], v[1], up);
    cswap(v[2], v[3], up);
  }
  {
    const bool up = ((t & 128) == 0);
    lds_pass(v, s, t, 64, up);
    reg_tail(v, t, up);
  }
  lds_pass(v, s, t, 128, true);
  lds_pass(v, s, t, 64, true);
  reg_tail(v, t, true);
}

__device__ inline void bmerge1024(float v[4], float* s, int t) {
  lds_pass(v, s, t, 128, true);
  lds_pass(v, s, t, 64, true);
  reg_tail(v, t, true);
}

// ---------------- kernel 3: fused stats-finalize + sorts + merge ------------
// 128 blocks: blk<64 -> Q row (sort 4 chunks, merge to top-1024);
//             blk>=64 -> K row (mean of 4 channels, sort).
__global__ __launch_bounds__(256) void sortmerge_kernel(
    const float* __restrict__ conv, const float* __restrict__ psum,
    const float* __restrict__ psumsq, const float* __restrict__ bng,
    const float* __restrict__ bnb, float* __restrict__ Qt,
    float* __restrict__ Kt) {
  __shared__ float s[1024];
  __shared__ float sred[8];
  __shared__ float cm[4], cr[4];
  const int t = threadIdx.x, blk = blockIdx.x;
  const bool isQ = blk < 64;
  const int row = isQ ? blk : blk - 64;
  const int hp = row & 7;
  const int fi = row >> 4;
  const int bb = ((row >> 3) & 1) * 4 + (hp >> 1);
  const int chbase = (isQ ? 0 : 32) + fi * 8 + (hp & 1) * 4;
  // finalize BN stats for this row's 4 channels
  if (t < 8) {
    const float* src = (t < 4) ? psum : psumsq;
    const int ch = chbase + (t & 3);
    float a = 0.f;
    for (int i = 0; i < 32; ++i) a += src[ch * 32 + i];
    sred[t] = a;
  }
  __syncthreads();
  if (t < 4) {
    const float mean = sred[t] * (1.f / 8192.f);
    const float var = sred[4 + t] * (1.f / 8192.f) - mean * mean;
    cm[t] = mean;
    cr[t] = rsqrtf(fmaxf(var, 0.f) + 1e-5f);
  }
  __syncthreads();
  if (isQ) {
    const float* base = conv + (size_t)(fi * 8 + bb) * 8192;
    float c0[4], c1[4], c2[4], c3[4];
#pragma unroll
    for (int jc = 0; jc < 4; ++jc) {
      float* v = jc == 0 ? c0 : jc == 1 ? c1 : jc == 2 ? c2 : c3;
      const int hh = (hp & 1) * 4 + jc;
      const float mean = cm[jc], rstd = cr[jc];
      const float g = bng[hh], be = bnb[hh];
      const float4 x = *(const float4*)&base[hh * 1024 + 4 * t];
      v[0] = bn_elu(x.x, mean, rstd, g, be);
      v[1] = bn_elu(x.y, mean, rstd, g, be);
      v[2] = bn_elu(x.z, mean, rstd, g, be);
      v[3] = bn_elu(x.w, mean, rstd, g, be);
      sort1024(v, s, t);
    }
    float a[4], b[4];
    // a = top-1024 of c0 U c1
    *(float4*)&s[4 * t] = make_float4(c1[0], c1[1], c1[2], c1[3]);
    __syncthreads();
#pragma unroll
    for (int e = 0; e < 4; ++e) a[e] = fmaxf(c0[e], s[1023 - 4 * t - e]);
    __syncthreads();
    bmerge1024(a, s, t);
    // b = top-1024 of c2 U c3
    *(float4*)&s[4 * t] = make_float4(c3[0], c3[1], c3[2], c3[3]);
    __syncthreads();
#pragma unroll
    for (int e = 0; e < 4; ++e) b[e] = fmaxf(c2[e], s[1023 - 4 * t - e]);
    __syncthreads();
    bmerge1024(b, s, t);
    // final top-1024 of a U b
    *(float4*)&s[4 * t] = make_float4(b[0], b[1], b[2], b[3]);
    __syncthreads();
#pragma unroll
    for (int e = 0; e < 4; ++e) a[e] = fmaxf(a[e], s[1023 - 4 * t - e]);
    __syncthreads();
    bmerge1024(a, s, t);
    *(float4*)&Qt[(size_t)row * 1024 + 4 * t] =
        make_float4(a[0], a[1], a[2], a[3]);
  } else {
    float v[4];
    float sum0 = 0.f, sum1 = 0.f, sum2 = 0.f, sum3 = 0.f;
#pragma unroll
    for (int j = 0; j < 4; ++j) {
      const int hh = (hp & 1) * 4 + j;
      const float mean = cm[j], rstd = cr[j];
      const float g = bng[hh], be = bnb[hh];
      const float4 x = *(const float4*)&conv[(size_t)(4 + fi) * 64 * 1024 +
                                             (size_t)bb * 8192 + hh * 1024 +
                                             4 * t];
      sum0 += bn_elu(x.x, mean, rstd, g, be);
      sum1 += bn_elu(x.y, mean, rstd, g, be);
      sum2 += bn_elu(x.z, mean, rstd, g, be);
      sum3 += bn_elu(x.w, mean, rstd, g, be);
    }
    v[0] = sum0 * 0.25f;
    v[1] = sum1 * 0.25f;
    v[2] = sum2 * 0.25f;
    v[3] = sum3 * 0.25f;
    sort1024(v, s, t);
    *(float4*)&Kt[(size_t)row * 1024 + 4 * t] =
        make_float4(v[0], v[1], v[2], v[3]);
  }
}

// ---------------- kernel 4: softmax + attn write + MFMA PV (v5) -------------
// grid 1024 = 64 bh x 16 q-tiles of 64 rows; 256 threads (4 waves).
// Same structure as v4; conversions use compiler bf16 casts (cvt_pk), and
// c = dot(W_bq,W_bk)/8 computed per-wave (stats kernel removed).
__global__ __launch_bounds__(256, 4) void attn5_kernel(
    const float* __restrict__ V, const float* __restrict__ Qt,
    const float* __restrict__ Kt, const float* __restrict__ Wbq,
    const float* __restrict__ Wbk, float* __restrict__ ctx,
    float* __restrict__ attn) {
  __shared__ float Kts[1024];
  __shared__ float sq[64], mq[64], rz[64];
  __shared__ short Vhi[2][8 * 64 * 8];  // [buf][ko][d][8k] bf16
  __shared__ short Vlo[2][8 * 64 * 8];
  const int tid = threadIdx.x;
  const int b = blockIdx.x;
  // XCD swizzle: all 16 q-tiles of one bh on one XCD (1024 % 8 == 0).
  const int bh = ((b & 7) << 3) | ((b >> 3) & 7);
  const int qt = b >> 6;  // 0..15
  const int qbase = qt * 64;
  const int lane0 = tid & 63;
  float cval;
  {
    float d = Wbq[lane0] * Wbk[lane0];
#pragma unroll
    for (int mm = 32; mm >= 1; mm >>= 1) d += __shfl_xor(d, mm, 64);
    cval = d * 0.125f;  // / sqrt(64)
  }
  const float* Ktg = Kt + (size_t)bh * 1024;
  for (int t = tid; t < 1024; t += 256) Kts[t] = Ktg[t];
  const float kHi = Ktg[0], kLo = Ktg[1023];  // sorted descending
  if (tid < 64) {
    const float s = cval * Qt[(size_t)bh * 1024 + qbase + tid];
    sq[tid] = s;
    mq[tid] = fmaxf(s * kHi, s * kLo);
  }
  __syncthreads();
  {  // Z pass: 4 threads per q-row
    const int row = tid >> 2, qtr = tid & 3;
    const float s = sq[row], m = mq[row];
    float z = 0.f;
    const int k0 = qtr * 256;
    for (int k = 0; k < 256; ++k) z += __expf(fmaf(s, Kts[k0 + k], -m));
    z += __shfl_xor(z, 1, 64);
    z += __shfl_xor(z, 2, 64);
    if (qtr == 0) rz[row] = 1.f / z;
  }
  __syncthreads();

  const int wv = tid >> 6, l = tid & 63;
  const int l15 = l & 15, l4 = l >> 4;
  const int q = wv * 16 + l15;  // this lane's A-frag row
  const float s = sq[q], m = mq[q], r = rz[q];
  f32x4 acc[4];
#pragma unroll
  for (int dt = 0; dt < 4; ++dt) acc[dt] = (f32x4){0.f, 0.f, 0.f, 0.f};

  const float* Vb = V + (size_t)bh * 65536;
  float* arow = attn + ((size_t)bh << 20) + (size_t)qbase * 1024;
  const int dV = tid & 63, kqV = tid >> 6;  // V-convert roles

  for (int ch = 0; ch < 16; ++ch) {
    const int kc = ch * 64;
    const int buf = ch & 1;
    // ---- (a) issue V global loads early (latency hides under E-phase) ----
    float vreg[2][8];
#pragma unroll
    for (int g = 0; g < 2; ++g) {
      const int ko = kqV + g * 4;
      const float* vs = Vb + (size_t)(kc + ko * 8) * 64 + dV;
#pragma unroll
      for (int i = 0; i < 8; ++i) vreg[g][i] = vs[i * 64];
    }
    // ---- (b) E-phase in registers: exp -> attn write -> bf16 hi/lo ----
    bf16x8 ahi[2], alo[2];
#pragma unroll
    for (int ks = 0; ks < 2; ++ks) {
      const int kb = kc + ks * 32 + l4 * 8;
      const float4 kv0 = *(const float4*)&Kts[kb];
      const float4 kv1 = *(const float4*)&Kts[kb + 4];
      float e[8];
      e[0] = __expf(fmaf(s, kv0.x, -m)) * r;
      e[1] = __expf(fmaf(s, kv0.y, -m)) * r;
      e[2] = __expf(fmaf(s, kv0.z, -m)) * r;
      e[3] = __expf(fmaf(s, kv0.w, -m)) * r;
      e[4] = __expf(fmaf(s, kv1.x, -m)) * r;
      e[5] = __expf(fmaf(s, kv1.y, -m)) * r;
      e[6] = __expf(fmaf(s, kv1.z, -m)) * r;
      e[7] = __expf(fmaf(s, kv1.w, -m)) * r;
      float* ag = arow + (size_t)q * 1024 + kb;
      *(float4*)ag = make_float4(e[0], e[1], e[2], e[3]);
      *(float4*)(ag + 4) = make_float4(e[4], e[5], e[6], e[7]);
      BF8 H, L;
#pragma unroll
      for (int i = 0; i < 8; ++i) {
        const __hip_bfloat16 hb = __float2bfloat16(e[i]);
        H.s[i] = __bfloat16_as_short(hb);
        L.s[i] =
            __bfloat16_as_short(__float2bfloat16(e[i] - __bfloat162float(hb)));
      }
      ahi[ks] = H.v;
      alo[ks] = L.v;
    }
    // ---- (c) convert V and commit to LDS B-frag layout ----
#pragma unroll
    for (int g = 0; g < 2; ++g) {
      const int ko = kqV + g * 4;
      BF8 H, L;
#pragma unroll
      for (int i = 0; i < 8; ++i) {
        const float f = vreg[g][i];
        const __hip_bfloat16 hb = __float2bfloat16(f);
        H.s[i] = __bfloat16_as_short(hb);
        L.s[i] =
            __bfloat16_as_short(__float2bfloat16(f - __bfloat162float(hb)));
      }
      *(bf16x8*)&Vhi[buf][(ko * 64 + dV) * 8] = H.v;
      *(bf16x8*)&Vlo[buf][(ko * 64 + dV) * 8] = L.v;
    }
    __syncthreads();
    // ---- (d) PV: A from regs, B from LDS; 3 split MFMAs per (ks, dt) ----
#pragma unroll
    for (int ks = 0; ks < 2; ++ks) {
      const int ko = ks * 4 + l4;
#pragma unroll
      for (int dt = 0; dt < 4; ++dt) {
        const bf16x8 bhv =
            *(const bf16x8*)&Vhi[buf][(ko * 64 + dt * 16 + l15) * 8];
        const bf16x8 blv =
            *(const bf16x8*)&Vlo[buf][(ko * 64 + dt * 16 + l15) * 8];
        acc[dt] = __builtin_amdgcn_mfma_f32_16x16x32_bf16(ahi[ks], bhv,
                                                          acc[dt], 0, 0, 0);
        acc[dt] = __builtin_amdgcn_mfma_f32_16x16x32_bf16(ahi[ks], blv,
                                                          acc[dt], 0, 0, 0);
        acc[dt] = __builtin_amdgcn_mfma_f32_16x16x32_bf16(alo[ks], bhv,
                                                          acc[dt], 0, 0, 0);
      }
    }
  }
  // ---- epilogue: ctx write (D: row = wv*16 + 4*l4 + r, col = dt*16 + l15)
  float* cb = ctx + ((size_t)bh * 1024 + qbase + wv * 16 + l4 * 4) * 64 + l15;
#pragma unroll
  for (int dt = 0; dt < 4; ++dt)
#pragma unroll
    for (int rr = 0; rr < 4; ++rr) cb[(size_t)rr * 64 + dt * 16] = acc[dt][rr];
}

}  // namespace

extern "C" void kernel_launch(void* const* d_in, const int* in_sizes, int n_in,
                              void* d_out, int out_size, void* d_ws,
                              size_t ws_size, hipStream_t stream) {
  const float* Q = (const float*)d_in[0];
  const float* K = (const float*)d_in[1];
  const float* V = (const float*)d_in[2];
  const float* Wpq = (const float*)d_in[3];
  const float* Wbq = (const float*)d_in[4];
  const float* Wbk = (const float*)d_in[5];
  const float* bng = (const float*)d_in[6];
  const float* bnb = (const float*)d_in[7];
  // d_in[8] = attn_mask (all ones, unused)
  const float* cqw[4] = {(const float*)d_in[9], (const float*)d_in[13],
                         (const float*)d_in[17], (const float*)d_in[21]};
  const float* cqb[4] = {(const float*)d_in[10], (const float*)d_in[14],
                         (const float*)d_in[18], (const float*)d_in[22]};
  const float* ckw[4] = {(const float*)d_in[11], (const float*)d_in[15],
                         (const float*)d_in[19], (const float*)d_in[23]};
  const float* ckb[4] = {(const float*)d_in[12], (const float*)d_in[16],
                         (const float*)d_in[20], (const float*)d_in[24]};

  float* ws = (float*)d_ws;
  float* proj = ws + PROJ_OFF;
  float* conv = ws + CONV_OFF;
  float* psum = ws + PS_OFF;
  float* psumsq = ws + PSS_OFF;
  float* Qtp = ws + QT_OFF;
  float* Ktp = ws + KT_OFF;
  float* ctx = (float*)d_out;
  float* attn = ctx + (size_t)8 * 8 * 1024 * 64;

  proj_kernel<<<512, 256, 0, stream>>>(Q, K, Wpq, proj);
  conv_kernel<<<256, 256, 0, stream>>>(
      proj, cqw[0], cqb[0], cqw[1], cqb[1], cqw[2], cqb[2], cqw[3], cqb[3],
      ckw[0], ckb[0], ckw[1], ckb[1], ckw[2], ckb[2], ckw[3], ckb[3], conv,
      psum, psumsq);
  sortmerge_kernel<<<128, 256, 0, stream>>>(conv, psum, psumsq, bng, bnb, Qtp,
                                            Ktp);
  attn5_kernel<<<1024, 256, 0, stream>>>(V, Qtp, Ktp, Wbq, Wbk, ctx, attn);
}